// Round 1
// 560.765 us; speedup vs baseline: 1.1036x; 1.1036x over previous
//
#include <hip/hip_runtime.h>

#define N_NODES 10000
#define N_EDGES 160000
#define HD 512
#define EDD 16

typedef unsigned short u16;
typedef __attribute__((ext_vector_type(8))) short bf16x8;
typedef __attribute__((ext_vector_type(4))) float f32x4;
typedef __attribute__((ext_vector_type(4))) unsigned short u16x4;

__device__ __forceinline__ float bf2f(u16 u){
  unsigned int x = ((unsigned int)u) << 16;
  return __builtin_bit_cast(float, x);
}
__device__ __forceinline__ u16 f2bf(float f){
  unsigned int x = __builtin_bit_cast(unsigned int, f);
  unsigned int r = (x + 0x7fffu + ((x >> 16) & 1u)) >> 16;
  return (u16)r;
}
// dtype-flagged scalar load/store: flag!=0 -> f32, else bf16
__device__ __forceinline__ float ldx(const void* p, long long i, int f32){
  return f32 ? ((const float*)p)[i] : bf2f(((const u16*)p)[i]);
}
__device__ __forceinline__ void stx(void* p, long long i, int f32, float v){
  if (f32) ((float*)p)[i] = v; else ((u16*)p)[i] = f2bf(v);
}
// tanh-form gelu: x*sigmoid(1.5957691216*x*(1+0.044715*x^2)); |err|<3e-4 vs erf
__device__ __forceinline__ float gelu_f(float x){
  float c = x * x;
  float a = x * (1.5957691216f + 0.0713548162f * c);
  a = fminf(fmaxf(a, -30.f), 30.f);
  float e = __expf(a);
  return x * e * __builtin_amdgcn_rcpf(e + 1.0f);
}
__device__ __forceinline__ f32x4 mfma16(bf16x8 a, bf16x8 b, f32x4 c){
  return __builtin_amdgcn_mfma_f32_16x16x32_bf16(a, b, c, 0, 0, 0);
}
// LDS slot swizzle for [row][32]-u16 tiles (4 x 16B slots per row):
// slot' = slot ^ ((row>>1)&3) -> even rows spread over all 4 bank-quads
__device__ __forceinline__ int swz8(int row, int slot){
  return (slot ^ ((row >> 1) & 3)) * 8;
}
// load 8 contiguous elems as bf16x8 from f32-or-bf16 source (8-elem aligned)
__device__ __forceinline__ bf16x8 ld8(const void* p, long long i, int f32){
  if (!f32) return *(const bf16x8*)((const u16*)p + i);
  const float* q = (const float*)p + i;
  float4 a = *(const float4*)q, b = *(const float4*)(q + 4);
  u16 t[8] = { f2bf(a.x), f2bf(a.y), f2bf(a.z), f2bf(a.w),
               f2bf(b.x), f2bf(b.y), f2bf(b.z), f2bf(b.w) };
  return *(const bf16x8*)t;
}
__device__ __forceinline__ void stage8(const void* src, long long idx, int f32, u16* dst){
  bf16x8 v = ld8(src, idx, f32);
  *(bf16x8*)dst = v;
}

// ---------------- dtype probe (proven in round 5)
__device__ __forceinline__ int probe_rand(const void* p, int l){
  const u16* q = (const u16*)p;
  float mx = 0.f;
  #pragma unroll
  for (int i = 0; i < 4; ++i) mx = fmaxf(mx, fabsf(bf2f(q[l * 4 + i])));
  #pragma unroll
  for (int m = 1; m < 64; m <<= 1) mx = fmaxf(mx, __shfl_xor(mx, m, 64));
  return (mx > 1e3f) ? 1 : 0;
}
// F[0]=h F[1]=ea F[2]=msg_w1 F[3]=msg_w2 F[4]=upd_w1 F[5]=upd_w2
// F[6]=em_w1 F[7]=em_w2 F[8]=eg_w F[9]=norm_g F[10]=en_g F[11]=out(=h)
__global__ __launch_bounds__(64) void kprobe(
    const void* h, const void* ea, const void* mw1, const void* mw2,
    const void* uw1, const void* uw2, const void* ew1, const void* ew2,
    const void* egw, const void* ng, const void* eng, int* F)
{
  const int l = threadIdx.x;
  int f0 = probe_rand(h, l),   f1 = probe_rand(ea, l),  f2 = probe_rand(mw1, l);
  int f3 = probe_rand(mw2, l), f4 = probe_rand(uw1, l), f5 = probe_rand(uw2, l);
  int f6 = probe_rand(ew1, l), f7 = probe_rand(ew2, l), f8 = probe_rand(egw, l);
  if (l == 0){
    F[0] = f0; F[1] = f1; F[2] = f2; F[3] = f3; F[4] = f4; F[5] = f5;
    F[6] = f6; F[7] = f7; F[8] = f8;
    F[9]  = (((const u16*)ng)[0]  == 0) ? 1 : 0;
    F[10] = (((const u16*)eng)[0] == 0) ? 1 : 0;
    F[11] = f0;
  }
}

__global__ void kfill(u16* __restrict__ out, long long n, float val){
  long long i = (long long)blockIdx.x * 256 + threadIdx.x;
  if (i < n) out[i] = f2bf(val);
}

// ---------------- h (f32|bf16) -> hB (bf16), 8 elems/thread, grid 2500
__global__ __launch_bounds__(256) void kcvt(const void* __restrict__ in,
                                            u16* __restrict__ out,
                                            const int* __restrict__ F){
  const int f32 = F[0];
  const long long i = ((long long)blockIdx.x * 256 + threadIdx.x) * 8;
  if (i < (long long)N_NODES * HD){
    bf16x8 v = ld8(in, i, f32);
    *(bf16x8*)(out + i) = v;
  }
}

__global__ void kdeg(const int* __restrict__ dst, int* __restrict__ deg){
  int e = blockIdx.x * 256 + threadIdx.x;
  if (e < N_EDGES) atomicAdd(&deg[dst[e]], 1);
}

// ---------------- exclusive scan of deg -> start (single block, 256 thr x 40)
__global__ __launch_bounds__(256) void kscan(const int* __restrict__ deg,
                                             int* __restrict__ start){
  __shared__ int ls[256];
  const int t = threadIdx.x;
  const int base = t * 40;
  int s = 0;
  for (int i = 0; i < 40; ++i){ int idx = base + i; if (idx < N_NODES) s += deg[idx]; }
  ls[t] = s; __syncthreads();
  for (int off = 1; off < 256; off <<= 1){
    int v = (t >= off) ? ls[t - off] : 0;
    __syncthreads();
    ls[t] += v;
    __syncthreads();
  }
  int run = (t == 0) ? 0 : ls[t - 1];
  for (int i = 0; i < 40; ++i){
    int idx = base + i;
    if (idx < N_NODES){ start[idx] = run; run += deg[idx]; }
  }
}

// ---------------- counting-sort scatter: edges sorted by dst
__global__ void kscatter(const int* __restrict__ srcI, const int* __restrict__ dstI,
                         const int* __restrict__ start, int* __restrict__ cursor,
                         int* __restrict__ sSrc, int* __restrict__ sDst,
                         int* __restrict__ sIdx){
  int e = blockIdx.x * 256 + threadIdx.x;
  if (e < N_EDGES){
    int d = dstI[e];
    int p = start[d] + atomicAdd(&cursor[d], 1);
    sSrc[p] = srcI[e]; sDst[p] = d; sIdx[p] = e;
  }
}

// ---------------- transpose+pad to bf16
__global__ void ktranspose(const void* __restrict__ in, u16* __restrict__ out,
                           int K, int N, int Kpad, int Nout,
                           const int* __restrict__ F, int fidx){
  const int f32 = F[fidx];
  int i = blockIdx.x * 256 + threadIdx.x;
  int total = Nout * Kpad;
  if (i >= total) return;
  int n = i / Kpad, k = i - n * Kpad;
  u16 v = 0;
  if (k < K) v = f2bf(ldx(in, (long long)k * N + n, f32));
  out[i] = v;
}

// ---------------- edge update (MFMA): e_new = LN(ea + 0.1*gate*delta) -> d_out
// gate logit computed via a second MFMA (B = eg_w broadcast to all 16 cols)
__global__ __launch_bounds__(256) void kedge(
    const u16* __restrict__ hB, const void* __restrict__ ea,
    const u16* __restrict__ WET, const void* __restrict__ egw,
    const void* __restrict__ em_b1, const void* __restrict__ em_w2,
    const void* __restrict__ em_b2, const void* __restrict__ eg_b,
    const void* __restrict__ en_g, const void* __restrict__ en_b,
    const int* __restrict__ F,
    const int* __restrict__ srcI, const int* __restrict__ dstI,
    void* __restrict__ dout)
{
  __shared__ u16 bt[16 * 1064];
  __shared__ u16 egs[1056];
  __shared__ float w2s[256];
  __shared__ float b1s[16], b2s[16], gns[16], bns[16];
  __shared__ float t_s[4][16][17];
  __shared__ float g_s[4][16];
  __shared__ float egb_s;
  const int tid = threadIdx.x;
  const int fea = F[1], fem1 = F[6], fem2 = F[7], feg = F[8];
  const int fen = F[10], fo = F[11];

  for (int i = tid; i < 16 * 132; i += 256){
    int r = i / 132, c = i - r * 132;
    *(uint4*)&bt[r * 1064 + c * 8] = *(const uint4*)&WET[r * 1056 + c * 8];
  }
  if (tid < 16){ uint4 z = {0,0,0,0}; *(uint4*)&bt[tid * 1064 + 1056] = z; }
  for (int i = tid; i < 1056; i += 256)
    egs[i] = (i < 1040) ? f2bf(ldx(egw, i, feg)) : (u16)0;
  w2s[tid] = ldx(em_w2, tid, fem2);
  if (tid < 16){
    b1s[tid] = ldx(em_b1, tid, fem1); b2s[tid] = ldx(em_b2, tid, fem2);
    gns[tid] = ldx(en_g, tid, fen);   bns[tid] = ldx(en_b, tid, fen);
  }
  if (tid == 0) egb_s = ldx(eg_b, 0, feg);
  __syncthreads();

  const int w = tid >> 6, l = tid & 63;
  const int lm = l & 15, kg = l >> 4;
  const u16* bp = &bt[lm * 1064 + kg * 8];
  const u16* ep = &egs[kg * 8];

  for (int it = 0; it < 4; ++it){
    const int tile  = blockIdx.x * 4 + it;
    const int ebase = tile * 64 + w * 16;
    const int e = ebase + lm;
    const int s = srcI[e], d = dstI[e];
    f32x4 acc = {0.f, 0.f, 0.f, 0.f};
    f32x4 gac = {0.f, 0.f, 0.f, 0.f};
    for (int kt = 0; kt < 33; ++kt){
      const int k = kt * 32 + kg * 8;
      bf16x8 av;
      if (k < 512)       av = *(const bf16x8*)(hB + (size_t)s * HD + k);
      else if (k < 1024) av = *(const bf16x8*)(hB + (size_t)d * HD + (k - 512));
      else if (k < 1040) av = ld8(ea, (long long)e * EDD + (k - 1024), fea);
      else { bf16x8 z = {0,0,0,0,0,0,0,0}; av = z; }
      bf16x8 bv = *(const bf16x8*)(bp + kt * 32);
      bf16x8 ev = *(const bf16x8*)(ep + kt * 32);
      acc = mfma16(av, bv, acc);
      gac = mfma16(av, ev, gac);
    }
    __syncthreads();
    #pragma unroll
    for (int r = 0; r < 4; ++r) t_s[w][kg * 4 + r][lm] = acc[r];
    if (lm == 0){
      #pragma unroll
      for (int r = 0; r < 4; ++r) g_s[w][kg * 4 + r] = gac[r];
    }
    __syncthreads();
    const int el = l >> 2, jq = l & 3, j0 = jq * 4;
    const int eg2 = ebase + el;
    const float gate = 1.f / (1.f + __expf(-(g_s[w][el] + egb_s)));
    float dlt[4] = {b2s[j0], b2s[j0 + 1], b2s[j0 + 2], b2s[j0 + 3]};
    #pragma unroll
    for (int i2 = 0; i2 < 16; ++i2){
      const float gi = gelu_f(t_s[w][el][i2] + b1s[i2]);
      #pragma unroll
      for (int jj = 0; jj < 4; ++jj) dlt[jj] += gi * w2s[i2 * 16 + j0 + jj];
    }
    float rv[4]; float s1 = 0.f, s2 = 0.f;
    #pragma unroll
    for (int jj = 0; jj < 4; ++jj){
      rv[jj] = ldx(ea, (long long)eg2 * EDD + j0 + jj, fea) + 0.1f * gate * dlt[jj];
      s1 += rv[jj]; s2 += rv[jj] * rv[jj];
    }
    s1 += __shfl_xor(s1, 1, 64); s2 += __shfl_xor(s2, 1, 64);
    s1 += __shfl_xor(s1, 2, 64); s2 += __shfl_xor(s2, 2, 64);
    const float mu  = s1 * (1.f / 16.f);
    const float var = s2 * (1.f / 16.f) - mu * mu;
    const float inv = rsqrtf(var + 1e-5f);
    const long long ob = (long long)N_NODES * HD + (long long)eg2 * EDD + j0;
    #pragma unroll
    for (int jj = 0; jj < 4; ++jj)
      stx(dout, ob + jj, fo, (rv[jj] - mu) * inv * gns[j0 + jj] + bns[j0 + jj]);
  }
}

// ---------------- message GEMM over SORTED edges with segmented-reduce epilogue
// S[dst] += gelu([h[src]|e_new] @ msg_w1 + b1); grid (1250,4), 128x128, K=544.
__global__ __launch_bounds__(256) void kmsg(
    const u16* __restrict__ hB, const void* __restrict__ dout,
    const u16* __restrict__ W1T, const void* __restrict__ msg_b1,
    const int* __restrict__ F,
    const int* __restrict__ sSrc, const int* __restrict__ sDst,
    const int* __restrict__ sIdx,
    float* __restrict__ agg)
{
  __shared__ u16 As[128 * 32];
  __shared__ u16 Bs[128 * 32];
  __shared__ float Sf[128 * 34];   // segmented-reduce tile (stride 34: 2-way banks)
  __shared__ int src_s[128];
  __shared__ int dst_s[128];
  __shared__ int idx_s[128];
  const int tid = threadIdx.x;
  const int fw = F[2], fo = F[11];
  const void* e_base = fo ? (const void*)((const float*)dout + (size_t)N_NODES * HD)
                          : (const void*)((const u16*)dout + (size_t)N_NODES * HD);
  const int row0 = blockIdx.x * 128, n0 = blockIdx.y * 128;
  if (tid < 128){
    src_s[tid] = sSrc[row0 + tid];
    dst_s[tid] = sDst[row0 + tid];
    idx_s[tid] = sIdx[row0 + tid];
  }
  __syncthreads();
  f32x4 acc[4][4];
  f32x4 z4 = {0.f, 0.f, 0.f, 0.f};
  #pragma unroll
  for (int i = 0; i < 4; ++i)
    #pragma unroll
    for (int j = 0; j < 4; ++j) acc[i][j] = z4;
  const int w = tid >> 6, l = tid & 63;
  const int wr = w >> 1, wc = w & 1, lm = l & 15, lk = l >> 4;
  // hoisted per-thread staging addresses (loop-invariant gathers)
  const int mA = tid >> 2, kqA = tid & 3;
  const u16* a0 = hB + (size_t)src_s[mA] * HD + kqA * 8;
  const u16* a1 = hB + (size_t)src_s[mA + 64] * HD + kqA * 8;
  const u16* b0 = W1T + (size_t)(n0 + mA) * 544 + kqA * 8;
  const u16* b1 = W1T + (size_t)(n0 + mA + 64) * 544 + kqA * 8;
  u16* dA0 = &As[mA * 32 + swz8(mA, kqA)];
  u16* dA1 = &As[(mA + 64) * 32 + swz8(mA + 64, kqA)];
  u16* dB0 = &Bs[mA * 32 + swz8(mA, kqA)];
  u16* dB1 = &Bs[(mA + 64) * 32 + swz8(mA + 64, kqA)];
  const long long eidx0 = (long long)idx_s[mA] * EDD + kqA * 8;
  const long long eidx1 = (long long)idx_s[mA + 64] * EDD + kqA * 8;
  for (int kt = 0; kt < 17; ++kt){
    const int kk = kt * 32;
    if (kt < 16){
      *(uint4*)dA0 = *(const uint4*)(a0 + kk);
      *(uint4*)dA1 = *(const uint4*)(a1 + kk);
    } else {
      if (kqA < 2){
        stage8(e_base, eidx0, fo, dA0);
        stage8(e_base, eidx1, fo, dA1);
      } else {
        uint4 z = {0,0,0,0};
        *(uint4*)dA0 = z; *(uint4*)dA1 = z;
      }
    }
    *(uint4*)dB0 = *(const uint4*)(b0 + kk);
    *(uint4*)dB1 = *(const uint4*)(b1 + kk);
    __syncthreads();
    bf16x8 af[4], bfv[4];
    #pragma unroll
    for (int i = 0; i < 4; ++i){
      const int R = wr * 64 + i * 16 + lm;
      af[i] = *(const bf16x8*)&As[R * 32 + swz8(R, lk)];
    }
    #pragma unroll
    for (int j = 0; j < 4; ++j){
      const int R = wc * 64 + j * 16 + lm;
      bfv[j] = *(const bf16x8*)&Bs[R * 32 + swz8(R, lk)];
    }
    #pragma unroll
    for (int i = 0; i < 4; ++i)
      #pragma unroll
      for (int j = 0; j < 4; ++j)
        acc[i][j] = mfma16(af[i], bfv[j], acc[i][j]);
    __syncthreads();
  }
  // epilogue: per j, dump 128x32 tile to LDS, segment-reduce over sorted dst runs
  for (int j = 0; j < 4; ++j){
    const int col = n0 + wc * 64 + j * 16 + lm;
    const float bias = ldx(msg_b1, col, fw);
    #pragma unroll
    for (int i = 0; i < 4; ++i)
      #pragma unroll
      for (int r = 0; r < 4; ++r)
        Sf[(wr * 64 + i * 16 + lk * 4 + r) * 34 + wc * 16 + lm] =
            gelu_f(acc[i][j][r] + bias);
    __syncthreads();
    const int cj = tid & 31, chunk = tid >> 5;
    const int acol = n0 + (cj >> 4) * 64 + j * 16 + (cj & 15);
    const int rbase = chunk * 16;
    float run = Sf[rbase * 34 + cj];
    int cur = dst_s[rbase];
    #pragma unroll 4
    for (int rr = 1; rr < 16; ++rr){
      const int dn = dst_s[rbase + rr];
      const float v = Sf[(rbase + rr) * 34 + cj];
      if (dn == cur) run += v;
      else { atomicAdd(&agg[(size_t)cur * HD + acol], run); run = v; cur = dn; }
    }
    atomicAdd(&agg[(size_t)cur * HD + acol], run);
    __syncthreads();
  }
}

// ---------------- aggM = bf16(S @ msg_w2 + deg*b2)   grid (79,4), K=512
__global__ __launch_bounds__(256) void kagg2(
    const float* __restrict__ S, const u16* __restrict__ W2T,
    const void* __restrict__ msg_b2, const int* __restrict__ F,
    const int* __restrict__ deg, u16* __restrict__ aggM)
{
  __shared__ u16 As[128 * 32];
  __shared__ u16 Bs[128 * 32];
  const int tid = threadIdx.x;
  const int fw = F[3];
  const int row0 = blockIdx.x * 128, n0 = blockIdx.y * 128;
  f32x4 acc[4][4];
  f32x4 z4 = {0.f, 0.f, 0.f, 0.f};
  #pragma unroll
  for (int i = 0; i < 4; ++i)
    #pragma unroll
    for (int j = 0; j < 4; ++j) acc[i][j] = z4;
  const int w = tid >> 6, l = tid & 63;
  const int wr = w >> 1, wc = w & 1, lm = l & 15, lk = l >> 4;
  const int am = tid >> 1, ah = tid & 1;
  const int agr = row0 + am;
  for (int kt = 0; kt < 16; ++kt){
    const int kk = kt * 32;
    u16 tmp[16];
    if (agr < N_NODES){
      const float4* sp = (const float4*)(S + (size_t)agr * HD + kk + ah * 16);
      #pragma unroll
      for (int q = 0; q < 4; ++q){
        float4 v = sp[q];
        tmp[q*4+0] = f2bf(v.x); tmp[q*4+1] = f2bf(v.y);
        tmp[q*4+2] = f2bf(v.z); tmp[q*4+3] = f2bf(v.w);
      }
    } else {
      #pragma unroll
      for (int q = 0; q < 16; ++q) tmp[q] = 0;
    }
    *(uint4*)&As[am * 32 + swz8(am, ah * 2)]     = *(uint4*)&tmp[0];
    *(uint4*)&As[am * 32 + swz8(am, ah * 2 + 1)] = *(uint4*)&tmp[8];
    #pragma unroll
    for (int i = 0; i < 2; ++i){
      int t = tid + i * 256;
      int n = t >> 2, kq = t & 3;
      *(uint4*)&Bs[n * 32 + swz8(n, kq)] = *(const uint4*)(W2T + (size_t)(n0 + n) * 512 + kk + kq * 8);
    }
    __syncthreads();
    bf16x8 af[4], bfv[4];
    #pragma unroll
    for (int i = 0; i < 4; ++i){
      const int R = wr * 64 + i * 16 + lm;
      af[i] = *(const bf16x8*)&As[R * 32 + swz8(R, lk)];
    }
    #pragma unroll
    for (int j = 0; j < 4; ++j){
      const int R = wc * 64 + j * 16 + lm;
      bfv[j] = *(const bf16x8*)&Bs[R * 32 + swz8(R, lk)];
    }
    #pragma unroll
    for (int i = 0; i < 4; ++i)
      #pragma unroll
      for (int j = 0; j < 4; ++j)
        acc[i][j] = mfma16(af[i], bfv[j], acc[i][j]);
    __syncthreads();
  }
  #pragma unroll
  for (int j = 0; j < 4; ++j){
    const int col = n0 + wc * 64 + j * 16 + lm;
    const float b2v = ldx(msg_b2, col, fw);
    #pragma unroll
    for (int i = 0; i < 4; ++i){
      const int rb = row0 + wr * 64 + i * 16 + lk * 4;
      #pragma unroll
      for (int r = 0; r < 4; ++r){
        int gr = rb + r;
        if (gr < N_NODES)
          aggM[(size_t)gr * HD + col] = f2bf(acc[i][j][r] + (float)deg[gr] * b2v);
      }
    }
  }
}

// ---------------- U = bf16(gelu([h|aggM] @ upd_w1 + b1))  grid (79,4), K=1024
__global__ __launch_bounds__(256) void kupd1(
    const u16* __restrict__ hB, const u16* __restrict__ aggM,
    const u16* __restrict__ WU1T, const void* __restrict__ upd_b1,
    const int* __restrict__ F, u16* __restrict__ U)
{
  __shared__ u16 As[128 * 32];
  __shared__ u16 Bs[128 * 32];
  const int tid = threadIdx.x;
  const int fw = F[4];
  const int row0 = blockIdx.x * 128, n0 = blockIdx.y * 128;
  f32x4 acc[4][4];
  f32x4 z4 = {0.f, 0.f, 0.f, 0.f};
  #pragma unroll
  for (int i = 0; i < 4; ++i)
    #pragma unroll
    for (int j = 0; j < 4; ++j) acc[i][j] = z4;
  const int w = tid >> 6, l = tid & 63;
  const int wr = w >> 1, wc = w & 1, lm = l & 15, lk = l >> 4;
  for (int kt = 0; kt < 32; ++kt){
    const int kk = kt * 32;
    #pragma unroll
    for (int i = 0; i < 2; ++i){
      int t = tid + i * 256;
      int m = t >> 2, kq = t & 3, c = kk + kq * 8;
      int gr = row0 + m; if (gr > N_NODES - 1) gr = N_NODES - 1;
      if (kk < 512) *(uint4*)&As[m * 32 + swz8(m, kq)] = *(const uint4*)(hB + (size_t)gr * HD + c);
      else          *(uint4*)&As[m * 32 + swz8(m, kq)] = *(const uint4*)(aggM + (size_t)gr * HD + (c - 512));
    }
    #pragma unroll
    for (int i = 0; i < 2; ++i){
      int t = tid + i * 256;
      int n = t >> 2, kq = t & 3;
      *(uint4*)&Bs[n * 32 + swz8(n, kq)] = *(const uint4*)(WU1T + (size_t)(n0 + n) * 1024 + kk + kq * 8);
    }
    __syncthreads();
    bf16x8 af[4], bfv[4];
    #pragma unroll
    for (int i = 0; i < 4; ++i){
      const int R = wr * 64 + i * 16 + lm;
      af[i] = *(const bf16x8*)&As[R * 32 + swz8(R, lk)];
    }
    #pragma unroll
    for (int j = 0; j < 4; ++j){
      const int R = wc * 64 + j * 16 + lm;
      bfv[j] = *(const bf16x8*)&Bs[R * 32 + swz8(R, lk)];
    }
    #pragma unroll
    for (int i = 0; i < 4; ++i)
      #pragma unroll
      for (int j = 0; j < 4; ++j)
        acc[i][j] = mfma16(af[i], bfv[j], acc[i][j]);
    __syncthreads();
  }
  #pragma unroll
  for (int j = 0; j < 4; ++j){
    const int col = n0 + wc * 64 + j * 16 + lm;
    const float bias = ldx(upd_b1, col, fw);
    #pragma unroll
    for (int i = 0; i < 4; ++i){
      const int rb = row0 + wr * 64 + i * 16 + lk * 4;
      #pragma unroll
      for (int r = 0; r < 4; ++r){
        int gr = rb + r;
        if (gr < N_NODES)
          U[(size_t)gr * HD + col] = f2bf(gelu_f(acc[i][j][r] + bias));
      }
    }
  }
}

// ---------------- h2b = bf16(U @ upd_w2 + b2)   grid (79,4), K=512
__global__ __launch_bounds__(256) void kupd2(
    const u16* __restrict__ U, const u16* __restrict__ WU2T,
    const void* __restrict__ upd_b2, const int* __restrict__ F,
    u16* __restrict__ h2b)
{
  __shared__ u16 As[128 * 32];
  __shared__ u16 Bs[128 * 32];
  const int tid = threadIdx.x;
  const int fw = F[5];
  const int row0 = blockIdx.x * 128, n0 = blockIdx.y * 128;
  f32x4 acc[4][4];
  f32x4 z4 = {0.f, 0.f, 0.f, 0.f};
  #pragma unroll
  for (int i = 0; i < 4; ++i)
    #pragma unroll
    for (int j = 0; j < 4; ++j) acc[i][j] = z4;
  const int w = tid >> 6, l = tid & 63;
  const int wr = w >> 1, wc = w & 1, lm = l & 15, lk = l >> 4;
  for (int kt = 0; kt < 16; ++kt){
    const int kk = kt * 32;
    #pragma unroll
    for (int i = 0; i < 2; ++i){
      int t = tid + i * 256;
      int m = t >> 2, kq = t & 3;
      int gr = row0 + m; if (gr > N_NODES - 1) gr = N_NODES - 1;
      *(uint4*)&As[m * 32 + swz8(m, kq)] = *(const uint4*)(U + (size_t)gr * HD + kk + kq * 8);
    }
    #pragma unroll
    for (int i = 0; i < 2; ++i){
      int t = tid + i * 256;
      int n = t >> 2, kq = t & 3;
      *(uint4*)&Bs[n * 32 + swz8(n, kq)] = *(const uint4*)(WU2T + (size_t)(n0 + n) * 512 + kk + kq * 8);
    }
    __syncthreads();
    bf16x8 af[4], bfv[4];
    #pragma unroll
    for (int i = 0; i < 4; ++i){
      const int R = wr * 64 + i * 16 + lm;
      af[i] = *(const bf16x8*)&As[R * 32 + swz8(R, lk)];
    }
    #pragma unroll
    for (int j = 0; j < 4; ++j){
      const int R = wc * 64 + j * 16 + lm;
      bfv[j] = *(const bf16x8*)&Bs[R * 32 + swz8(R, lk)];
    }
    #pragma unroll
    for (int i = 0; i < 4; ++i)
      #pragma unroll
      for (int j = 0; j < 4; ++j)
        acc[i][j] = mfma16(af[i], bfv[j], acc[i][j]);
    __syncthreads();
  }
  #pragma unroll
  for (int j = 0; j < 4; ++j){
    const int col = n0 + wc * 64 + j * 16 + lm;
    const float bias = ldx(upd_b2, col, fw);
    #pragma unroll
    for (int i = 0; i < 4; ++i){
      const int rb = row0 + wr * 64 + i * 16 + lk * 4;
      #pragma unroll
      for (int r = 0; r < 4; ++r){
        int gr = rb + r;
        if (gr < N_NODES)
          h2b[(size_t)gr * HD + col] = f2bf(acc[i][j][r] + bias);
      }
    }
  }
}

// ---------------- h_out = LN(h + h2)   grid 2500, 4 rows/block
__global__ __launch_bounds__(256) void kln(
    const void* __restrict__ h, const u16* __restrict__ h2b,
    const void* __restrict__ gg, const void* __restrict__ bbv,
    const int* __restrict__ F, void* __restrict__ dout)
{
  const int fh = F[0], fng = F[9], fo = F[11];
  const int w = threadIdx.x >> 6, l = threadIdx.x & 63;
  const int row = blockIdx.x * 4 + w;
  float x[8];
  #pragma unroll
  for (int j = 0; j < 8; ++j){
    const long long idx = (long long)row * HD + l * 8 + j;
    x[j] = ldx(h, idx, fh) + bf2f(h2b[idx]);
  }
  float s1 = 0.f, s2 = 0.f;
  #pragma unroll
  for (int j = 0; j < 8; ++j){ s1 += x[j]; s2 += x[j] * x[j]; }
  #pragma unroll
  for (int m = 1; m < 64; m <<= 1){ s1 += __shfl_xor(s1, m, 64); s2 += __shfl_xor(s2, m, 64); }
  const float mu  = s1 * (1.f / 512.f);
  const float var = s2 * (1.f / 512.f) - mu * mu;
  const float inv = rsqrtf(var + 1e-5f);
  #pragma unroll
  for (int j = 0; j < 8; ++j){
    const float gf = ldx(gg,  l * 8 + j, fng);
    const float bf = ldx(bbv, l * 8 + j, fng);
    stx(dout, (long long)row * HD + l * 8 + j, fo, (x[j] - mu) * inv * gf + bf);
  }
}

// ---------------- workspace layout (bytes), total 35,448,064 (verified fits)
#define OFF_S     0u            // N*512 f32 (scatter accum; aliased as U bf16)
#define OFF_DEG   20480000u     // N ints
#define OFF_CUR   20520000u     // N ints (sort cursors)
#define OFF_F     20560000u     // 16 ints
#define OFF_START 20560064u     // N ints
#define OFF_AGGM  20600064u     // N*512 bf16 (aliased as h2b)
#define OFF_W1T   30840064u     // 512*544 bf16
#define OFF_W2T   31397120u     // 512*512 bf16
#define OFF_WU1T  31921408u     // 512*1024 bf16
#define OFF_WU2T  32969984u     // 512*512 bf16
#define OFF_WET   33494272u     // 16*1056 bf16
#define OFF_SSRC  33528064u     // E ints
#define OFF_SDST  34168064u     // E ints
#define OFF_SIDX  34808064u     // E ints
#define WS_NEEDED 35448064u

extern "C" void kernel_launch(void* const* d_in, const int* in_sizes, int n_in,
                              void* d_out, int out_size, void* d_ws, size_t ws_size,
                              hipStream_t stream)
{
  const void* h      = d_in[0];
  const void* ea     = d_in[1];
  const void* msg_w1 = d_in[2];
  const void* msg_b1 = d_in[3];
  const void* msg_w2 = d_in[4];
  const void* msg_b2 = d_in[5];
  const void* upd_w1 = d_in[6];
  const void* upd_b1 = d_in[7];
  const void* upd_w2 = d_in[8];
  const void* upd_b2 = d_in[9];
  const void* norm_g = d_in[10];
  const void* norm_b = d_in[11];
  const void* em_w1  = d_in[12];
  const void* em_b1  = d_in[13];
  const void* em_w2  = d_in[14];
  const void* em_b2  = d_in[15];
  const void* eg_w   = d_in[16];
  const void* eg_b   = d_in[17];
  const void* en_g   = d_in[18];
  const void* en_b   = d_in[19];
  const int* eidx    = (const int*)d_in[20];
  const int* srcI = eidx;
  const int* dstI = eidx + N_EDGES;

  float sent = 0.f;
  if (ws_size < (size_t)WS_NEEDED)            sent = 1000.f;
  else if (n_in != 21)                        sent = 2000.f;
  else if (in_sizes[0]  != N_NODES * HD)      sent = 3000.f;
  else if (in_sizes[20] != 2 * N_EDGES)       sent = 4000.f;
  else if (out_size != N_NODES*HD + N_EDGES*EDD) sent = 5000.f;
  if (sent != 0.f){
    kfill<<<(out_size + 255)/256, 256, 0, stream>>>((u16*)d_out, out_size, sent);
    return;
  }

  char* ws = (char*)d_ws;
  float* S     = (float*)(ws + OFF_S);
  u16*   U     = (u16*)(ws + OFF_S);      // alias: after kagg2 consumed S
  int*   deg   = (int*)(ws + OFF_DEG);
  int*   cur   = (int*)(ws + OFF_CUR);
  int*   F     = (int*)(ws + OFF_F);
  int*   start = (int*)(ws + OFF_START);
  u16*   aggM  = (u16*)(ws + OFF_AGGM);
  u16*   h2b   = (u16*)(ws + OFF_AGGM);   // alias: after kupd1 consumed aggM
  u16*   W1T   = (u16*)(ws + OFF_W1T);
  u16*   W2T   = (u16*)(ws + OFF_W2T);
  u16*   WU1T  = (u16*)(ws + OFF_WU1T);
  u16*   WU2T  = (u16*)(ws + OFF_WU2T);
  u16*   WET   = (u16*)(ws + OFF_WET);
  int*   sSrc  = (int*)(ws + OFF_SSRC);
  int*   sDst  = (int*)(ws + OFF_SDST);
  int*   sIdx  = (int*)(ws + OFF_SIDX);

  // hB (bf16 h) lives in d_out's h_out region (dead until kln rewrites it).
  u16* hB = (u16*)d_out;

  // zero S + deg + cursors in one memset (contiguous)
  hipMemsetAsync(S, 0, (size_t)OFF_F, stream);

  kprobe<<<1, 64, 0, stream>>>(h, ea, msg_w1, msg_w2, upd_w1, upd_w2,
                               em_w1, em_w2, eg_w, norm_g, en_g, F);

  kcvt<<<2500, 256, 0, stream>>>(h, hB, F);

  ktranspose<<<(512*544  + 255)/256, 256, 0, stream>>>(msg_w1, W1T, 528, 512, 544, 512, F, 2);
  ktranspose<<<(512*512  + 255)/256, 256, 0, stream>>>(msg_w2, W2T, 512, 512, 512, 512, F, 3);
  ktranspose<<<(512*1024 + 255)/256, 256, 0, stream>>>(upd_w1, WU1T, 1024, 512, 1024, 512, F, 4);
  ktranspose<<<(512*512  + 255)/256, 256, 0, stream>>>(upd_w2, WU2T, 512, 512, 512, 512, F, 5);
  ktranspose<<<(16*1056  + 255)/256, 256, 0, stream>>>(em_w1, WET, 1040, 16, 1056, 16, F, 6);

  kdeg<<<(N_EDGES + 255)/256, 256, 0, stream>>>(dstI, deg);
  kscan<<<1, 256, 0, stream>>>(deg, start);
  kscatter<<<(N_EDGES + 255)/256, 256, 0, stream>>>(srcI, dstI, start, cur,
                                                    sSrc, sDst, sIdx);

  kedge<<<625, 256, 0, stream>>>(hB, ea, WET, eg_w, em_b1, em_w2, em_b2, eg_b,
                                 en_g, en_b, F, srcI, dstI, d_out);
  kmsg<<<dim3(1250, 4), 256, 0, stream>>>(hB, d_out, W1T, msg_b1, F,
                                          sSrc, sDst, sIdx, S);
  kagg2<<<dim3(79, 4), 256, 0, stream>>>(S, W2T, msg_b2, F, deg, aggM);
  kupd1<<<dim3(79, 4), 256, 0, stream>>>(hB, aggM, WU1T, upd_b1, F, U);
  kupd2<<<dim3(79, 4), 256, 0, stream>>>(U, WU2T, upd_b2, F, h2b);
  kln<<<2500, 256, 0, stream>>>(h, h2b, norm_g, norm_b, F, d_out);
}

// Round 2
// 553.473 us; speedup vs baseline: 1.1181x; 1.0132x over previous
//
#include <hip/hip_runtime.h>

#define N_NODES 10000
#define N_EDGES 160000
#define HD 512
#define EDD 16

typedef unsigned short u16;
typedef __attribute__((ext_vector_type(8))) short bf16x8;
typedef __attribute__((ext_vector_type(4))) float f32x4;
typedef __attribute__((ext_vector_type(4))) unsigned short u16x4;

__device__ __forceinline__ float bf2f(u16 u){
  unsigned int x = ((unsigned int)u) << 16;
  return __builtin_bit_cast(float, x);
}
__device__ __forceinline__ u16 f2bf(float f){
  unsigned int x = __builtin_bit_cast(unsigned int, f);
  unsigned int r = (x + 0x7fffu + ((x >> 16) & 1u)) >> 16;
  return (u16)r;
}
// dtype-flagged scalar load/store: flag!=0 -> f32, else bf16
__device__ __forceinline__ float ldx(const void* p, long long i, int f32){
  return f32 ? ((const float*)p)[i] : bf2f(((const u16*)p)[i]);
}
__device__ __forceinline__ void stx(void* p, long long i, int f32, float v){
  if (f32) ((float*)p)[i] = v; else ((u16*)p)[i] = f2bf(v);
}
// tanh-form gelu, NaN-free sigmoid form: x * rcp(1 + e^{-a});
// a->+inf: e=0 -> x; a->-inf: e=inf -> rcp(inf)=0. No clamps needed.
__device__ __forceinline__ float gelu_f(float x){
  float c = x * x;
  float a = x * (1.5957691216f + 0.0713548162f * c);
  float e = __expf(-a);
  return x * __builtin_amdgcn_rcpf(1.0f + e);
}
__device__ __forceinline__ f32x4 mfma16(bf16x8 a, bf16x8 b, f32x4 c){
  return __builtin_amdgcn_mfma_f32_16x16x32_bf16(a, b, c, 0, 0, 0);
}
// LDS slot swizzle for [row][32]-u16 tiles (4 x 16B slots per row):
// slot' = slot ^ ((row>>1)&3) -> even rows spread over all 4 bank-quads
__device__ __forceinline__ int swz8(int row, int slot){
  return (slot ^ ((row >> 1) & 3)) * 8;
}
// load 8 contiguous elems as bf16x8 from f32-or-bf16 source (8-elem aligned)
__device__ __forceinline__ bf16x8 ld8(const void* p, long long i, int f32){
  if (!f32) return *(const bf16x8*)((const u16*)p + i);
  const float* q = (const float*)p + i;
  float4 a = *(const float4*)q, b = *(const float4*)(q + 4);
  u16 t[8] = { f2bf(a.x), f2bf(a.y), f2bf(a.z), f2bf(a.w),
               f2bf(b.x), f2bf(b.y), f2bf(b.z), f2bf(b.w) };
  return *(const bf16x8*)t;
}
__device__ __forceinline__ void stage8(const void* src, long long idx, int f32, u16* dst){
  bf16x8 v = ld8(src, idx, f32);
  *(bf16x8*)dst = v;
}

// ---------------- dtype probe (proven in round 5)
__device__ __forceinline__ int probe_rand(const void* p, int l){
  const u16* q = (const u16*)p;
  float mx = 0.f;
  #pragma unroll
  for (int i = 0; i < 4; ++i) mx = fmaxf(mx, fabsf(bf2f(q[l * 4 + i])));
  #pragma unroll
  for (int m = 1; m < 64; m <<= 1) mx = fmaxf(mx, __shfl_xor(mx, m, 64));
  return (mx > 1e3f) ? 1 : 0;
}
// F[0]=h F[1]=ea F[2]=msg_w1 F[3]=msg_w2 F[4]=upd_w1 F[5]=upd_w2
// F[6]=em_w1 F[7]=em_w2 F[8]=eg_w F[9]=norm_g F[10]=en_g F[11]=out(=h)
__global__ __launch_bounds__(64) void kprobe(
    const void* h, const void* ea, const void* mw1, const void* mw2,
    const void* uw1, const void* uw2, const void* ew1, const void* ew2,
    const void* egw, const void* ng, const void* eng, int* F)
{
  const int l = threadIdx.x;
  int f0 = probe_rand(h, l),   f1 = probe_rand(ea, l),  f2 = probe_rand(mw1, l);
  int f3 = probe_rand(mw2, l), f4 = probe_rand(uw1, l), f5 = probe_rand(uw2, l);
  int f6 = probe_rand(ew1, l), f7 = probe_rand(ew2, l), f8 = probe_rand(egw, l);
  if (l == 0){
    F[0] = f0; F[1] = f1; F[2] = f2; F[3] = f3; F[4] = f4; F[5] = f5;
    F[6] = f6; F[7] = f7; F[8] = f8;
    F[9]  = (((const u16*)ng)[0]  == 0) ? 1 : 0;
    F[10] = (((const u16*)eng)[0] == 0) ? 1 : 0;
    F[11] = f0;
  }
}

__global__ void kfill(u16* __restrict__ out, long long n, float val){
  long long i = (long long)blockIdx.x * 256 + threadIdx.x;
  if (i < n) out[i] = f2bf(val);
}

// ---------------- h (f32|bf16) -> hB (bf16), 8 elems/thread, grid 2500
__global__ __launch_bounds__(256) void kcvt(const void* __restrict__ in,
                                            u16* __restrict__ out,
                                            const int* __restrict__ F){
  const int f32 = F[0];
  const long long i = ((long long)blockIdx.x * 256 + threadIdx.x) * 8;
  if (i < (long long)N_NODES * HD){
    bf16x8 v = ld8(in, i, f32);
    *(bf16x8*)(out + i) = v;
  }
}

__global__ void kdeg(const int* __restrict__ dst, int* __restrict__ deg){
  int e = blockIdx.x * 256 + threadIdx.x;
  if (e < N_EDGES) atomicAdd(&deg[dst[e]], 1);
}

// ---------------- exclusive scan of deg -> start (single block, 256 thr x 40)
__global__ __launch_bounds__(256) void kscan(const int* __restrict__ deg,
                                             int* __restrict__ start){
  __shared__ int ls[256];
  const int t = threadIdx.x;
  const int base = t * 40;
  int s = 0;
  for (int i = 0; i < 40; ++i){ int idx = base + i; if (idx < N_NODES) s += deg[idx]; }
  ls[t] = s; __syncthreads();
  for (int off = 1; off < 256; off <<= 1){
    int v = (t >= off) ? ls[t - off] : 0;
    __syncthreads();
    ls[t] += v;
    __syncthreads();
  }
  int run = (t == 0) ? 0 : ls[t - 1];
  for (int i = 0; i < 40; ++i){
    int idx = base + i;
    if (idx < N_NODES){ start[idx] = run; run += deg[idx]; }
  }
}

// ---------------- counting-sort scatter: edges sorted by dst
__global__ void kscatter(const int* __restrict__ srcI, const int* __restrict__ dstI,
                         const int* __restrict__ start, int* __restrict__ cursor,
                         int* __restrict__ sSrc, int* __restrict__ sDst,
                         int* __restrict__ sIdx){
  int e = blockIdx.x * 256 + threadIdx.x;
  if (e < N_EDGES){
    int d = dstI[e];
    int p = start[d] + atomicAdd(&cursor[d], 1);
    sSrc[p] = srcI[e]; sDst[p] = d; sIdx[p] = e;
  }
}

// ---------------- transpose+pad to bf16
__global__ void ktranspose(const void* __restrict__ in, u16* __restrict__ out,
                           int K, int N, int Kpad, int Nout,
                           const int* __restrict__ F, int fidx){
  const int f32 = F[fidx];
  int i = blockIdx.x * 256 + threadIdx.x;
  int total = Nout * Kpad;
  if (i >= total) return;
  int n = i / Kpad, k = i - n * Kpad;
  u16 v = 0;
  if (k < K) v = f2bf(ldx(in, (long long)k * N + n, f32));
  out[i] = v;
}

// ---------------- edge update (MFMA): e_new = LN(ea + 0.1*gate*delta) -> d_out
// gate logit computed via a second MFMA (B = eg_w broadcast to all 16 cols)
__global__ __launch_bounds__(256) void kedge(
    const u16* __restrict__ hB, const void* __restrict__ ea,
    const u16* __restrict__ WET, const void* __restrict__ egw,
    const void* __restrict__ em_b1, const void* __restrict__ em_w2,
    const void* __restrict__ em_b2, const void* __restrict__ eg_b,
    const void* __restrict__ en_g, const void* __restrict__ en_b,
    const int* __restrict__ F,
    const int* __restrict__ srcI, const int* __restrict__ dstI,
    void* __restrict__ dout)
{
  __shared__ u16 bt[16 * 1064];
  __shared__ u16 egs[1056];
  __shared__ float w2s[256];
  __shared__ float b1s[16], b2s[16], gns[16], bns[16];
  __shared__ float t_s[4][16][17];
  __shared__ float g_s[4][16];
  __shared__ float egb_s;
  const int tid = threadIdx.x;
  const int fea = F[1], fem1 = F[6], fem2 = F[7], feg = F[8];
  const int fen = F[10], fo = F[11];

  for (int i = tid; i < 16 * 132; i += 256){
    int r = i / 132, c = i - r * 132;
    *(uint4*)&bt[r * 1064 + c * 8] = *(const uint4*)&WET[r * 1056 + c * 8];
  }
  if (tid < 16){ uint4 z = {0,0,0,0}; *(uint4*)&bt[tid * 1064 + 1056] = z; }
  for (int i = tid; i < 1056; i += 256)
    egs[i] = (i < 1040) ? f2bf(ldx(egw, i, feg)) : (u16)0;
  w2s[tid] = ldx(em_w2, tid, fem2);
  if (tid < 16){
    b1s[tid] = ldx(em_b1, tid, fem1); b2s[tid] = ldx(em_b2, tid, fem2);
    gns[tid] = ldx(en_g, tid, fen);   bns[tid] = ldx(en_b, tid, fen);
  }
  if (tid == 0) egb_s = ldx(eg_b, 0, feg);
  __syncthreads();

  const int w = tid >> 6, l = tid & 63;
  const int lm = l & 15, kg = l >> 4;
  const u16* bp = &bt[lm * 1064 + kg * 8];
  const u16* ep = &egs[kg * 8];

  for (int it = 0; it < 4; ++it){
    const int tile  = blockIdx.x * 4 + it;
    const int ebase = tile * 64 + w * 16;
    const int e = ebase + lm;
    const int s = srcI[e], d = dstI[e];
    f32x4 acc = {0.f, 0.f, 0.f, 0.f};
    f32x4 gac = {0.f, 0.f, 0.f, 0.f};
    for (int kt = 0; kt < 33; ++kt){
      const int k = kt * 32 + kg * 8;
      bf16x8 av;
      if (k < 512)       av = *(const bf16x8*)(hB + (size_t)s * HD + k);
      else if (k < 1024) av = *(const bf16x8*)(hB + (size_t)d * HD + (k - 512));
      else if (k < 1040) av = ld8(ea, (long long)e * EDD + (k - 1024), fea);
      else { bf16x8 z = {0,0,0,0,0,0,0,0}; av = z; }
      bf16x8 bv = *(const bf16x8*)(bp + kt * 32);
      bf16x8 ev = *(const bf16x8*)(ep + kt * 32);
      acc = mfma16(av, bv, acc);
      gac = mfma16(av, ev, gac);
    }
    __syncthreads();
    #pragma unroll
    for (int r = 0; r < 4; ++r) t_s[w][kg * 4 + r][lm] = acc[r];
    if (lm == 0){
      #pragma unroll
      for (int r = 0; r < 4; ++r) g_s[w][kg * 4 + r] = gac[r];
    }
    __syncthreads();
    const int el = l >> 2, jq = l & 3, j0 = jq * 4;
    const int eg2 = ebase + el;
    const float gate = 1.f / (1.f + __expf(-(g_s[w][el] + egb_s)));
    float dlt[4] = {b2s[j0], b2s[j0 + 1], b2s[j0 + 2], b2s[j0 + 3]};
    #pragma unroll
    for (int i2 = 0; i2 < 16; ++i2){
      const float gi = gelu_f(t_s[w][el][i2] + b1s[i2]);
      #pragma unroll
      for (int jj = 0; jj < 4; ++jj) dlt[jj] += gi * w2s[i2 * 16 + j0 + jj];
    }
    float rv[4]; float s1 = 0.f, s2 = 0.f;
    #pragma unroll
    for (int jj = 0; jj < 4; ++jj){
      rv[jj] = ldx(ea, (long long)eg2 * EDD + j0 + jj, fea) + 0.1f * gate * dlt[jj];
      s1 += rv[jj]; s2 += rv[jj] * rv[jj];
    }
    s1 += __shfl_xor(s1, 1, 64); s2 += __shfl_xor(s2, 1, 64);
    s1 += __shfl_xor(s1, 2, 64); s2 += __shfl_xor(s2, 2, 64);
    const float mu  = s1 * (1.f / 16.f);
    const float var = s2 * (1.f / 16.f) - mu * mu;
    const float inv = rsqrtf(var + 1e-5f);
    const long long ob = (long long)N_NODES * HD + (long long)eg2 * EDD + j0;
    #pragma unroll
    for (int jj = 0; jj < 4; ++jj)
      stx(dout, ob + jj, fo, (rv[jj] - mu) * inv * gns[j0 + jj] + bns[j0 + jj]);
  }
}

// ---------------- message GEMM over SORTED edges with segmented-reduce epilogue
// S[dst] += gelu([h[src]|e_new] @ msg_w1 + b1); grid (1250,4), 128x128, K=544.
// LDS union: As/Bs (K-loop) alias Sf (epilogue) -> 18.9 KB total, ~6 blocks/CU.
__global__ __launch_bounds__(256) void kmsg(
    const u16* __restrict__ hB, const void* __restrict__ dout,
    const u16* __restrict__ W1T, const void* __restrict__ msg_b1,
    const int* __restrict__ F,
    const int* __restrict__ sSrc, const int* __restrict__ sDst,
    const int* __restrict__ sIdx,
    float* __restrict__ agg)
{
  __shared__ __align__(16) float SMEM[4352];  // max(As+Bs=16384B, Sf=17408B)
  u16*   As = (u16*)SMEM;                     // [128*32] u16, K-loop only
  u16*   Bs = (u16*)SMEM + 128 * 32;          // [128*32] u16, K-loop only
  float* Sf = SMEM;                           // [128*34] f32, epilogue only
  __shared__ int src_s[128];
  __shared__ int dst_s[128];
  __shared__ int idx_s[128];
  const int tid = threadIdx.x;
  const int fw = F[2], fo = F[11];
  const void* e_base = fo ? (const void*)((const float*)dout + (size_t)N_NODES * HD)
                          : (const void*)((const u16*)dout + (size_t)N_NODES * HD);
  const int row0 = blockIdx.x * 128, n0 = blockIdx.y * 128;
  if (tid < 128){
    src_s[tid] = sSrc[row0 + tid];
    dst_s[tid] = sDst[row0 + tid];
    idx_s[tid] = sIdx[row0 + tid];
  }
  __syncthreads();
  f32x4 acc[4][4];
  f32x4 z4 = {0.f, 0.f, 0.f, 0.f};
  #pragma unroll
  for (int i = 0; i < 4; ++i)
    #pragma unroll
    for (int j = 0; j < 4; ++j) acc[i][j] = z4;
  const int w = tid >> 6, l = tid & 63;
  const int wr = w >> 1, wc = w & 1, lm = l & 15, lk = l >> 4;
  // hoisted per-thread staging addresses (loop-invariant gathers)
  const int mA = tid >> 2, kqA = tid & 3;
  const u16* a0 = hB + (size_t)src_s[mA] * HD + kqA * 8;
  const u16* a1 = hB + (size_t)src_s[mA + 64] * HD + kqA * 8;
  const u16* b0 = W1T + (size_t)(n0 + mA) * 544 + kqA * 8;
  const u16* b1 = W1T + (size_t)(n0 + mA + 64) * 544 + kqA * 8;
  u16* dA0 = As + mA * 32 + swz8(mA, kqA);
  u16* dA1 = As + (mA + 64) * 32 + swz8(mA + 64, kqA);
  u16* dB0 = Bs + mA * 32 + swz8(mA, kqA);
  u16* dB1 = Bs + (mA + 64) * 32 + swz8(mA + 64, kqA);
  const long long eidx0 = (long long)idx_s[mA] * EDD + kqA * 8;
  const long long eidx1 = (long long)idx_s[mA + 64] * EDD + kqA * 8;
  for (int kt = 0; kt < 17; ++kt){
    const int kk = kt * 32;
    if (kt < 16){
      *(uint4*)dA0 = *(const uint4*)(a0 + kk);
      *(uint4*)dA1 = *(const uint4*)(a1 + kk);
    } else {
      if (kqA < 2){
        stage8(e_base, eidx0, fo, dA0);
        stage8(e_base, eidx1, fo, dA1);
      } else {
        uint4 z = {0,0,0,0};
        *(uint4*)dA0 = z; *(uint4*)dA1 = z;
      }
    }
    *(uint4*)dB0 = *(const uint4*)(b0 + kk);
    *(uint4*)dB1 = *(const uint4*)(b1 + kk);
    __syncthreads();
    bf16x8 af[4], bfv[4];
    #pragma unroll
    for (int i = 0; i < 4; ++i){
      const int R = wr * 64 + i * 16 + lm;
      af[i] = *(const bf16x8*)(As + R * 32 + swz8(R, lk));
    }
    #pragma unroll
    for (int j = 0; j < 4; ++j){
      const int R = wc * 64 + j * 16 + lm;
      bfv[j] = *(const bf16x8*)(Bs + R * 32 + swz8(R, lk));
    }
    #pragma unroll
    for (int i = 0; i < 4; ++i)
      #pragma unroll
      for (int j = 0; j < 4; ++j)
        acc[i][j] = mfma16(af[i], bfv[j], acc[i][j]);
    __syncthreads();
  }
  // epilogue: per j, dump 128x32 tile to LDS, segment-reduce over sorted dst runs
  for (int j = 0; j < 4; ++j){
    const int col = n0 + wc * 64 + j * 16 + lm;
    const float bias = ldx(msg_b1, col, fw);
    #pragma unroll
    for (int i = 0; i < 4; ++i)
      #pragma unroll
      for (int r = 0; r < 4; ++r)
        Sf[(wr * 64 + i * 16 + lk * 4 + r) * 34 + wc * 16 + lm] =
            gelu_f(acc[i][j][r] + bias);
    __syncthreads();
    const int cj = tid & 31, chunk = tid >> 5;
    const int acol = n0 + (cj >> 4) * 64 + j * 16 + (cj & 15);
    const int rbase = chunk * 16;
    float run = Sf[rbase * 34 + cj];
    int cur = dst_s[rbase];
    #pragma unroll 4
    for (int rr = 1; rr < 16; ++rr){
      const int dn = dst_s[rbase + rr];
      const float v = Sf[(rbase + rr) * 34 + cj];
      if (dn == cur) run += v;
      else { atomicAdd(&agg[(size_t)cur * HD + acol], run); run = v; cur = dn; }
    }
    atomicAdd(&agg[(size_t)cur * HD + acol], run);
    __syncthreads();
  }
}

// ---------------- aggM = bf16(S @ msg_w2 + deg*b2)   grid (79,4), K=512
__global__ __launch_bounds__(256) void kagg2(
    const float* __restrict__ S, const u16* __restrict__ W2T,
    const void* __restrict__ msg_b2, const int* __restrict__ F,
    const int* __restrict__ deg, u16* __restrict__ aggM)
{
  __shared__ u16 As[128 * 32];
  __shared__ u16 Bs[128 * 32];
  const int tid = threadIdx.x;
  const int fw = F[3];
  const int row0 = blockIdx.x * 128, n0 = blockIdx.y * 128;
  f32x4 acc[4][4];
  f32x4 z4 = {0.f, 0.f, 0.f, 0.f};
  #pragma unroll
  for (int i = 0; i < 4; ++i)
    #pragma unroll
    for (int j = 0; j < 4; ++j) acc[i][j] = z4;
  const int w = tid >> 6, l = tid & 63;
  const int wr = w >> 1, wc = w & 1, lm = l & 15, lk = l >> 4;
  const int am = tid >> 1, ah = tid & 1;
  const int agr = row0 + am;
  for (int kt = 0; kt < 16; ++kt){
    const int kk = kt * 32;
    u16 tmp[16];
    if (agr < N_NODES){
      const float4* sp = (const float4*)(S + (size_t)agr * HD + kk + ah * 16);
      #pragma unroll
      for (int q = 0; q < 4; ++q){
        float4 v = sp[q];
        tmp[q*4+0] = f2bf(v.x); tmp[q*4+1] = f2bf(v.y);
        tmp[q*4+2] = f2bf(v.z); tmp[q*4+3] = f2bf(v.w);
      }
    } else {
      #pragma unroll
      for (int q = 0; q < 16; ++q) tmp[q] = 0;
    }
    *(uint4*)&As[am * 32 + swz8(am, ah * 2)]     = *(uint4*)&tmp[0];
    *(uint4*)&As[am * 32 + swz8(am, ah * 2 + 1)] = *(uint4*)&tmp[8];
    #pragma unroll
    for (int i = 0; i < 2; ++i){
      int t = tid + i * 256;
      int n = t >> 2, kq = t & 3;
      *(uint4*)&Bs[n * 32 + swz8(n, kq)] = *(const uint4*)(W2T + (size_t)(n0 + n) * 512 + kk + kq * 8);
    }
    __syncthreads();
    bf16x8 af[4], bfv[4];
    #pragma unroll
    for (int i = 0; i < 4; ++i){
      const int R = wr * 64 + i * 16 + lm;
      af[i] = *(const bf16x8*)&As[R * 32 + swz8(R, lk)];
    }
    #pragma unroll
    for (int j = 0; j < 4; ++j){
      const int R = wc * 64 + j * 16 + lm;
      bfv[j] = *(const bf16x8*)&Bs[R * 32 + swz8(R, lk)];
    }
    #pragma unroll
    for (int i = 0; i < 4; ++i)
      #pragma unroll
      for (int j = 0; j < 4; ++j)
        acc[i][j] = mfma16(af[i], bfv[j], acc[i][j]);
    __syncthreads();
  }
  #pragma unroll
  for (int j = 0; j < 4; ++j){
    const int col = n0 + wc * 64 + j * 16 + lm;
    const float b2v = ldx(msg_b2, col, fw);
    #pragma unroll
    for (int i = 0; i < 4; ++i){
      const int rb = row0 + wr * 64 + i * 16 + lk * 4;
      #pragma unroll
      for (int r = 0; r < 4; ++r){
        int gr = rb + r;
        if (gr < N_NODES)
          aggM[(size_t)gr * HD + col] = f2bf(acc[i][j][r] + (float)deg[gr] * b2v);
      }
    }
  }
}

// ---------------- U = bf16(gelu([h|aggM] @ upd_w1 + b1))  grid (79,4), K=1024
__global__ __launch_bounds__(256) void kupd1(
    const u16* __restrict__ hB, const u16* __restrict__ aggM,
    const u16* __restrict__ WU1T, const void* __restrict__ upd_b1,
    const int* __restrict__ F, u16* __restrict__ U)
{
  __shared__ u16 As[128 * 32];
  __shared__ u16 Bs[128 * 32];
  const int tid = threadIdx.x;
  const int fw = F[4];
  const int row0 = blockIdx.x * 128, n0 = blockIdx.y * 128;
  f32x4 acc[4][4];
  f32x4 z4 = {0.f, 0.f, 0.f, 0.f};
  #pragma unroll
  for (int i = 0; i < 4; ++i)
    #pragma unroll
    for (int j = 0; j < 4; ++j) acc[i][j] = z4;
  const int w = tid >> 6, l = tid & 63;
  const int wr = w >> 1, wc = w & 1, lm = l & 15, lk = l >> 4;
  for (int kt = 0; kt < 32; ++kt){
    const int kk = kt * 32;
    #pragma unroll
    for (int i = 0; i < 2; ++i){
      int t = tid + i * 256;
      int m = t >> 2, kq = t & 3, c = kk + kq * 8;
      int gr = row0 + m; if (gr > N_NODES - 1) gr = N_NODES - 1;
      if (kk < 512) *(uint4*)&As[m * 32 + swz8(m, kq)] = *(const uint4*)(hB + (size_t)gr * HD + c);
      else          *(uint4*)&As[m * 32 + swz8(m, kq)] = *(const uint4*)(aggM + (size_t)gr * HD + (c - 512));
    }
    #pragma unroll
    for (int i = 0; i < 2; ++i){
      int t = tid + i * 256;
      int n = t >> 2, kq = t & 3;
      *(uint4*)&Bs[n * 32 + swz8(n, kq)] = *(const uint4*)(WU1T + (size_t)(n0 + n) * 1024 + kk + kq * 8);
    }
    __syncthreads();
    bf16x8 af[4], bfv[4];
    #pragma unroll
    for (int i = 0; i < 4; ++i){
      const int R = wr * 64 + i * 16 + lm;
      af[i] = *(const bf16x8*)&As[R * 32 + swz8(R, lk)];
    }
    #pragma unroll
    for (int j = 0; j < 4; ++j){
      const int R = wc * 64 + j * 16 + lm;
      bfv[j] = *(const bf16x8*)&Bs[R * 32 + swz8(R, lk)];
    }
    #pragma unroll
    for (int i = 0; i < 4; ++i)
      #pragma unroll
      for (int j = 0; j < 4; ++j)
        acc[i][j] = mfma16(af[i], bfv[j], acc[i][j]);
    __syncthreads();
  }
  #pragma unroll
  for (int j = 0; j < 4; ++j){
    const int col = n0 + wc * 64 + j * 16 + lm;
    const float bias = ldx(upd_b1, col, fw);
    #pragma unroll
    for (int i = 0; i < 4; ++i){
      const int rb = row0 + wr * 64 + i * 16 + lk * 4;
      #pragma unroll
      for (int r = 0; r < 4; ++r){
        int gr = rb + r;
        if (gr < N_NODES)
          U[(size_t)gr * HD + col] = f2bf(gelu_f(acc[i][j][r] + bias));
      }
    }
  }
}

// ---------------- h2b = bf16(U @ upd_w2 + b2)   grid (79,4), K=512
__global__ __launch_bounds__(256) void kupd2(
    const u16* __restrict__ U, const u16* __restrict__ WU2T,
    const void* __restrict__ upd_b2, const int* __restrict__ F,
    u16* __restrict__ h2b)
{
  __shared__ u16 As[128 * 32];
  __shared__ u16 Bs[128 * 32];
  const int tid = threadIdx.x;
  const int fw = F[5];
  const int row0 = blockIdx.x * 128, n0 = blockIdx.y * 128;
  f32x4 acc[4][4];
  f32x4 z4 = {0.f, 0.f, 0.f, 0.f};
  #pragma unroll
  for (int i = 0; i < 4; ++i)
    #pragma unroll
    for (int j = 0; j < 4; ++j) acc[i][j] = z4;
  const int w = tid >> 6, l = tid & 63;
  const int wr = w >> 1, wc = w & 1, lm = l & 15, lk = l >> 4;
  for (int kt = 0; kt < 16; ++kt){
    const int kk = kt * 32;
    #pragma unroll
    for (int i = 0; i < 2; ++i){
      int t = tid + i * 256;
      int m = t >> 2, kq = t & 3;
      int gr = row0 + m; if (gr > N_NODES - 1) gr = N_NODES - 1;
      *(uint4*)&As[m * 32 + swz8(m, kq)] = *(const uint4*)(U + (size_t)gr * HD + kk + kq * 8);
    }
    #pragma unroll
    for (int i = 0; i < 2; ++i){
      int t = tid + i * 256;
      int n = t >> 2, kq = t & 3;
      *(uint4*)&Bs[n * 32 + swz8(n, kq)] = *(const uint4*)(WU2T + (size_t)(n0 + n) * 512 + kk + kq * 8);
    }
    __syncthreads();
    bf16x8 af[4], bfv[4];
    #pragma unroll
    for (int i = 0; i < 4; ++i){
      const int R = wr * 64 + i * 16 + lm;
      af[i] = *(const bf16x8*)&As[R * 32 + swz8(R, lk)];
    }
    #pragma unroll
    for (int j = 0; j < 4; ++j){
      const int R = wc * 64 + j * 16 + lm;
      bfv[j] = *(const bf16x8*)&Bs[R * 32 + swz8(R, lk)];
    }
    #pragma unroll
    for (int i = 0; i < 4; ++i)
      #pragma unroll
      for (int j = 0; j < 4; ++j)
        acc[i][j] = mfma16(af[i], bfv[j], acc[i][j]);
    __syncthreads();
  }
  #pragma unroll
  for (int j = 0; j < 4; ++j){
    const int col = n0 + wc * 64 + j * 16 + lm;
    const float bias = ldx(upd_b2, col, fw);
    #pragma unroll
    for (int i = 0; i < 4; ++i){
      const int rb = row0 + wr * 64 + i * 16 + lk * 4;
      #pragma unroll
      for (int r = 0; r < 4; ++r){
        int gr = rb + r;
        if (gr < N_NODES)
          h2b[(size_t)gr * HD + col] = f2bf(acc[i][j][r] + bias);
      }
    }
  }
}

// ---------------- h_out = LN(h + h2)   grid 2500, 4 rows/block
__global__ __launch_bounds__(256) void kln(
    const void* __restrict__ h, const u16* __restrict__ h2b,
    const void* __restrict__ gg, const void* __restrict__ bbv,
    const int* __restrict__ F, void* __restrict__ dout)
{
  const int fh = F[0], fng = F[9], fo = F[11];
  const int w = threadIdx.x >> 6, l = threadIdx.x & 63;
  const int row = blockIdx.x * 4 + w;
  float x[8];
  #pragma unroll
  for (int j = 0; j < 8; ++j){
    const long long idx = (long long)row * HD + l * 8 + j;
    x[j] = ldx(h, idx, fh) + bf2f(h2b[idx]);
  }
  float s1 = 0.f, s2 = 0.f;
  #pragma unroll
  for (int j = 0; j < 8; ++j){ s1 += x[j]; s2 += x[j] * x[j]; }
  #pragma unroll
  for (int m = 1; m < 64; m <<= 1){ s1 += __shfl_xor(s1, m, 64); s2 += __shfl_xor(s2, m, 64); }
  const float mu  = s1 * (1.f / 512.f);
  const float var = s2 * (1.f / 512.f) - mu * mu;
  const float inv = rsqrtf(var + 1e-5f);
  #pragma unroll
  for (int j = 0; j < 8; ++j){
    const float gf = ldx(gg,  l * 8 + j, fng);
    const float bf = ldx(bbv, l * 8 + j, fng);
    stx(dout, (long long)row * HD + l * 8 + j, fo, (x[j] - mu) * inv * gf + bf);
  }
}

// ---------------- workspace layout (bytes), total 35,448,064 (verified fits)
#define OFF_S     0u            // N*512 f32 (scatter accum; aliased as U bf16)
#define OFF_DEG   20480000u     // N ints
#define OFF_CUR   20520000u     // N ints (sort cursors)
#define OFF_F     20560000u     // 16 ints
#define OFF_START 20560064u     // N ints
#define OFF_AGGM  20600064u     // N*512 bf16 (aliased as h2b)
#define OFF_W1T   30840064u     // 512*544 bf16
#define OFF_W2T   31397120u     // 512*512 bf16
#define OFF_WU1T  31921408u     // 512*1024 bf16
#define OFF_WU2T  32969984u     // 512*512 bf16
#define OFF_WET   33494272u     // 16*1056 bf16
#define OFF_SSRC  33528064u     // E ints
#define OFF_SDST  34168064u     // E ints
#define OFF_SIDX  34808064u     // E ints
#define WS_NEEDED 35448064u

extern "C" void kernel_launch(void* const* d_in, const int* in_sizes, int n_in,
                              void* d_out, int out_size, void* d_ws, size_t ws_size,
                              hipStream_t stream)
{
  const void* h      = d_in[0];
  const void* ea     = d_in[1];
  const void* msg_w1 = d_in[2];
  const void* msg_b1 = d_in[3];
  const void* msg_w2 = d_in[4];
  const void* msg_b2 = d_in[5];
  const void* upd_w1 = d_in[6];
  const void* upd_b1 = d_in[7];
  const void* upd_w2 = d_in[8];
  const void* upd_b2 = d_in[9];
  const void* norm_g = d_in[10];
  const void* norm_b = d_in[11];
  const void* em_w1  = d_in[12];
  const void* em_b1  = d_in[13];
  const void* em_w2  = d_in[14];
  const void* em_b2  = d_in[15];
  const void* eg_w   = d_in[16];
  const void* eg_b   = d_in[17];
  const void* en_g   = d_in[18];
  const void* en_b   = d_in[19];
  const int* eidx    = (const int*)d_in[20];
  const int* srcI = eidx;
  const int* dstI = eidx + N_EDGES;

  float sent = 0.f;
  if (ws_size < (size_t)WS_NEEDED)            sent = 1000.f;
  else if (n_in != 21)                        sent = 2000.f;
  else if (in_sizes[0]  != N_NODES * HD)      sent = 3000.f;
  else if (in_sizes[20] != 2 * N_EDGES)       sent = 4000.f;
  else if (out_size != N_NODES*HD + N_EDGES*EDD) sent = 5000.f;
  if (sent != 0.f){
    kfill<<<(out_size + 255)/256, 256, 0, stream>>>((u16*)d_out, out_size, sent);
    return;
  }

  char* ws = (char*)d_ws;
  float* S     = (float*)(ws + OFF_S);
  u16*   U     = (u16*)(ws + OFF_S);      // alias: after kagg2 consumed S
  int*   deg   = (int*)(ws + OFF_DEG);
  int*   cur   = (int*)(ws + OFF_CUR);
  int*   F     = (int*)(ws + OFF_F);
  int*   start = (int*)(ws + OFF_START);
  u16*   aggM  = (u16*)(ws + OFF_AGGM);
  u16*   h2b   = (u16*)(ws + OFF_AGGM);   // alias: after kupd1 consumed aggM
  u16*   W1T   = (u16*)(ws + OFF_W1T);
  u16*   W2T   = (u16*)(ws + OFF_W2T);
  u16*   WU1T  = (u16*)(ws + OFF_WU1T);
  u16*   WU2T  = (u16*)(ws + OFF_WU2T);
  u16*   WET   = (u16*)(ws + OFF_WET);
  int*   sSrc  = (int*)(ws + OFF_SSRC);
  int*   sDst  = (int*)(ws + OFF_SDST);
  int*   sIdx  = (int*)(ws + OFF_SIDX);

  // hB (bf16 h) lives in d_out's h_out region (dead until kln rewrites it).
  u16* hB = (u16*)d_out;

  // zero S + deg + cursors in one memset (contiguous)
  hipMemsetAsync(S, 0, (size_t)OFF_F, stream);

  kprobe<<<1, 64, 0, stream>>>(h, ea, msg_w1, msg_w2, upd_w1, upd_w2,
                               em_w1, em_w2, eg_w, norm_g, en_g, F);

  kcvt<<<2500, 256, 0, stream>>>(h, hB, F);

  ktranspose<<<(512*544  + 255)/256, 256, 0, stream>>>(msg_w1, W1T, 528, 512, 544, 512, F, 2);
  ktranspose<<<(512*512  + 255)/256, 256, 0, stream>>>(msg_w2, W2T, 512, 512, 512, 512, F, 3);
  ktranspose<<<(512*1024 + 255)/256, 256, 0, stream>>>(upd_w1, WU1T, 1024, 512, 1024, 512, F, 4);
  ktranspose<<<(512*512  + 255)/256, 256, 0, stream>>>(upd_w2, WU2T, 512, 512, 512, 512, F, 5);
  ktranspose<<<(16*1056  + 255)/256, 256, 0, stream>>>(em_w1, WET, 1040, 16, 1056, 16, F, 6);

  kdeg<<<(N_EDGES + 255)/256, 256, 0, stream>>>(dstI, deg);
  kscan<<<1, 256, 0, stream>>>(deg, start);
  kscatter<<<(N_EDGES + 255)/256, 256, 0, stream>>>(srcI, dstI, start, cur,
                                                    sSrc, sDst, sIdx);

  kedge<<<625, 256, 0, stream>>>(hB, ea, WET, eg_w, em_b1, em_w2, em_b2, eg_b,
                                 en_g, en_b, F, srcI, dstI, d_out);
  kmsg<<<dim3(1250, 4), 256, 0, stream>>>(hB, d_out, W1T, msg_b1, F,
                                          sSrc, sDst, sIdx, S);
  kagg2<<<dim3(79, 4), 256, 0, stream>>>(S, W2T, msg_b2, F, deg, aggM);
  kupd1<<<dim3(79, 4), 256, 0, stream>>>(hB, aggM, WU1T, upd_b1, F, U);
  kupd2<<<dim3(79, 4), 256, 0, stream>>>(U, WU2T, upd_b2, F, h2b);
  kln<<<2500, 256, 0, stream>>>(h, h2b, norm_g, norm_b, F, d_out);
}

// Round 3
// 524.713 us; speedup vs baseline: 1.1794x; 1.0548x over previous
//
#include <hip/hip_runtime.h>

#define N_NODES 10000
#define N_EDGES 160000
#define HD 512
#define EDD 16

typedef unsigned short u16;
typedef __attribute__((ext_vector_type(8))) short bf16x8;
typedef __attribute__((ext_vector_type(4))) float f32x4;
typedef __attribute__((ext_vector_type(4))) unsigned short u16x4;

__device__ __forceinline__ float bf2f(u16 u){
  unsigned int x = ((unsigned int)u) << 16;
  return __builtin_bit_cast(float, x);
}
__device__ __forceinline__ u16 f2bf(float f){
  unsigned int x = __builtin_bit_cast(unsigned int, f);
  unsigned int r = (x + 0x7fffu + ((x >> 16) & 1u)) >> 16;
  return (u16)r;
}
// dtype-flagged scalar load/store: flag!=0 -> f32, else bf16
__device__ __forceinline__ float ldx(const void* p, long long i, int f32){
  return f32 ? ((const float*)p)[i] : bf2f(((const u16*)p)[i]);
}
__device__ __forceinline__ void stx(void* p, long long i, int f32, float v){
  if (f32) ((float*)p)[i] = v; else ((u16*)p)[i] = f2bf(v);
}
// tanh-form gelu, NaN-free sigmoid form: x * rcp(1 + e^{-a})
__device__ __forceinline__ float gelu_f(float x){
  float c = x * x;
  float a = x * (1.5957691216f + 0.0713548162f * c);
  float e = __expf(-a);
  return x * __builtin_amdgcn_rcpf(1.0f + e);
}
__device__ __forceinline__ f32x4 mfma16(bf16x8 a, bf16x8 b, f32x4 c){
  return __builtin_amdgcn_mfma_f32_16x16x32_bf16(a, b, c, 0, 0, 0);
}
// LDS slot swizzle for [row][32]-u16 tiles (4 x 16B slots per row):
// slot' = slot ^ ((row>>1)&3) -> even rows spread over all 4 bank-quads
__device__ __forceinline__ int swz8(int row, int slot){
  return (slot ^ ((row >> 1) & 3)) * 8;
}
// load 8 contiguous elems as bf16x8 from f32-or-bf16 source (8-elem aligned)
__device__ __forceinline__ bf16x8 ld8(const void* p, long long i, int f32){
  if (!f32) return *(const bf16x8*)((const u16*)p + i);
  const float* q = (const float*)p + i;
  float4 a = *(const float4*)q, b = *(const float4*)(q + 4);
  u16 t[8] = { f2bf(a.x), f2bf(a.y), f2bf(a.z), f2bf(a.w),
               f2bf(b.x), f2bf(b.y), f2bf(b.z), f2bf(b.w) };
  return *(const bf16x8*)t;
}
__device__ __forceinline__ void stage8(const void* src, long long idx, int f32, u16* dst){
  bf16x8 v = ld8(src, idx, f32);
  *(bf16x8*)dst = v;
}

// ---------------- dtype probe (proven in round 5)
__device__ __forceinline__ int probe_rand(const void* p, int l){
  const u16* q = (const u16*)p;
  float mx = 0.f;
  #pragma unroll
  for (int i = 0; i < 4; ++i) mx = fmaxf(mx, fabsf(bf2f(q[l * 4 + i])));
  #pragma unroll
  for (int m = 1; m < 64; m <<= 1) mx = fmaxf(mx, __shfl_xor(mx, m, 64));
  return (mx > 1e3f) ? 1 : 0;
}
// F[0]=h F[1]=ea F[2]=msg_w1 F[3]=msg_w2 F[4]=upd_w1 F[5]=upd_w2
// F[6]=em_w1 F[7]=em_w2 F[8]=eg_w F[9]=norm_g F[10]=en_g F[11]=out(=h)
__global__ __launch_bounds__(64) void kprobe(
    const void* h, const void* ea, const void* mw1, const void* mw2,
    const void* uw1, const void* uw2, const void* ew1, const void* ew2,
    const void* egw, const void* ng, const void* eng, int* F)
{
  const int l = threadIdx.x;
  int f0 = probe_rand(h, l),   f1 = probe_rand(ea, l),  f2 = probe_rand(mw1, l);
  int f3 = probe_rand(mw2, l), f4 = probe_rand(uw1, l), f5 = probe_rand(uw2, l);
  int f6 = probe_rand(ew1, l), f7 = probe_rand(ew2, l), f8 = probe_rand(egw, l);
  if (l == 0){
    F[0] = f0; F[1] = f1; F[2] = f2; F[3] = f3; F[4] = f4; F[5] = f5;
    F[6] = f6; F[7] = f7; F[8] = f8;
    F[9]  = (((const u16*)ng)[0]  == 0) ? 1 : 0;
    F[10] = (((const u16*)eng)[0] == 0) ? 1 : 0;
    F[11] = f0;
  }
}

__global__ void kfill(u16* __restrict__ out, long long n, float val){
  long long i = (long long)blockIdx.x * 256 + threadIdx.x;
  if (i < n) out[i] = f2bf(val);
}

// ---------------- h (f32|bf16) -> hB (bf16), 8 elems/thread, grid 2500
__global__ __launch_bounds__(256) void kcvt(const void* __restrict__ in,
                                            u16* __restrict__ out,
                                            const int* __restrict__ F){
  const int f32 = F[0];
  const long long i = ((long long)blockIdx.x * 256 + threadIdx.x) * 8;
  if (i < (long long)N_NODES * HD){
    bf16x8 v = ld8(in, i, f32);
    *(bf16x8*)(out + i) = v;
  }
}

__global__ void kdeg(const int* __restrict__ dst, int* __restrict__ deg){
  int e = blockIdx.x * 256 + threadIdx.x;
  if (e < N_EDGES) atomicAdd(&deg[dst[e]], 1);
}

// ---------------- exclusive scan of deg -> start (single block, 256 thr x 40)
__global__ __launch_bounds__(256) void kscan(const int* __restrict__ deg,
                                             int* __restrict__ start){
  __shared__ int ls[256];
  const int t = threadIdx.x;
  const int base = t * 40;
  int s = 0;
  for (int i = 0; i < 40; ++i){ int idx = base + i; if (idx < N_NODES) s += deg[idx]; }
  ls[t] = s; __syncthreads();
  for (int off = 1; off < 256; off <<= 1){
    int v = (t >= off) ? ls[t - off] : 0;
    __syncthreads();
    ls[t] += v;
    __syncthreads();
  }
  int run = (t == 0) ? 0 : ls[t - 1];
  for (int i = 0; i < 40; ++i){
    int idx = base + i;
    if (idx < N_NODES){ start[idx] = run; run += deg[idx]; }
  }
}

// ---------------- counting-sort scatter: edges sorted by dst
__global__ void kscatter(const int* __restrict__ srcI, const int* __restrict__ dstI,
                         const int* __restrict__ start, int* __restrict__ cursor,
                         int* __restrict__ sSrc, int* __restrict__ sDst,
                         int* __restrict__ sIdx){
  int e = blockIdx.x * 256 + threadIdx.x;
  if (e < N_EDGES){
    int d = dstI[e];
    int p = start[d] + atomicAdd(&cursor[d], 1);
    sSrc[p] = srcI[e]; sDst[p] = d; sIdx[p] = e;
  }
}

// ---------------- transpose+pad to bf16
__global__ void ktranspose(const void* __restrict__ in, u16* __restrict__ out,
                           int K, int N, int Kpad, int Nout,
                           const int* __restrict__ F, int fidx){
  const int f32 = F[fidx];
  int i = blockIdx.x * 256 + threadIdx.x;
  int total = Nout * Kpad;
  if (i >= total) return;
  int n = i / Kpad, k = i - n * Kpad;
  u16 v = 0;
  if (k < K) v = f2bf(ldx(in, (long long)k * N + n, f32));
  out[i] = v;
}

// ---------------- edge update (MFMA): e_new = LN(ea + 0.1*gate*delta) -> d_out
// gate logit computed via a second MFMA (B = eg_w broadcast to all 16 cols)
__global__ __launch_bounds__(256) void kedge(
    const u16* __restrict__ hB, const void* __restrict__ ea,
    const u16* __restrict__ WET, const void* __restrict__ egw,
    const void* __restrict__ em_b1, const void* __restrict__ em_w2,
    const void* __restrict__ em_b2, const void* __restrict__ eg_b,
    const void* __restrict__ en_g, const void* __restrict__ en_b,
    const int* __restrict__ F,
    const int* __restrict__ srcI, const int* __restrict__ dstI,
    void* __restrict__ dout)
{
  __shared__ u16 bt[16 * 1064];
  __shared__ u16 egs[1056];
  __shared__ float w2s[256];
  __shared__ float b1s[16], b2s[16], gns[16], bns[16];
  __shared__ float t_s[4][16][17];
  __shared__ float g_s[4][16];
  __shared__ float egb_s;
  const int tid = threadIdx.x;
  const int fea = F[1], fem1 = F[6], fem2 = F[7], feg = F[8];
  const int fen = F[10], fo = F[11];

  for (int i = tid; i < 16 * 132; i += 256){
    int r = i / 132, c = i - r * 132;
    *(uint4*)&bt[r * 1064 + c * 8] = *(const uint4*)&WET[r * 1056 + c * 8];
  }
  if (tid < 16){ uint4 z = {0,0,0,0}; *(uint4*)&bt[tid * 1064 + 1056] = z; }
  for (int i = tid; i < 1056; i += 256)
    egs[i] = (i < 1040) ? f2bf(ldx(egw, i, feg)) : (u16)0;
  w2s[tid] = ldx(em_w2, tid, fem2);
  if (tid < 16){
    b1s[tid] = ldx(em_b1, tid, fem1); b2s[tid] = ldx(em_b2, tid, fem2);
    gns[tid] = ldx(en_g, tid, fen);   bns[tid] = ldx(en_b, tid, fen);
  }
  if (tid == 0) egb_s = ldx(eg_b, 0, feg);
  __syncthreads();

  const int w = tid >> 6, l = tid & 63;
  const int lm = l & 15, kg = l >> 4;
  const u16* bp = &bt[lm * 1064 + kg * 8];
  const u16* ep = &egs[kg * 8];

  for (int it = 0; it < 4; ++it){
    const int tile  = blockIdx.x * 4 + it;
    const int ebase = tile * 64 + w * 16;
    const int e = ebase + lm;
    const int s = srcI[e], d = dstI[e];
    f32x4 acc = {0.f, 0.f, 0.f, 0.f};
    f32x4 gac = {0.f, 0.f, 0.f, 0.f};
    for (int kt = 0; kt < 33; ++kt){
      const int k = kt * 32 + kg * 8;
      bf16x8 av;
      if (k < 512)       av = *(const bf16x8*)(hB + (size_t)s * HD + k);
      else if (k < 1024) av = *(const bf16x8*)(hB + (size_t)d * HD + (k - 512));
      else if (k < 1040) av = ld8(ea, (long long)e * EDD + (k - 1024), fea);
      else { bf16x8 z = {0,0,0,0,0,0,0,0}; av = z; }
      bf16x8 bv = *(const bf16x8*)(bp + kt * 32);
      bf16x8 ev = *(const bf16x8*)(ep + kt * 32);
      acc = mfma16(av, bv, acc);
      gac = mfma16(av, ev, gac);
    }
    __syncthreads();
    #pragma unroll
    for (int r = 0; r < 4; ++r) t_s[w][kg * 4 + r][lm] = acc[r];
    if (lm == 0){
      #pragma unroll
      for (int r = 0; r < 4; ++r) g_s[w][kg * 4 + r] = gac[r];
    }
    __syncthreads();
    const int el = l >> 2, jq = l & 3, j0 = jq * 4;
    const int eg2 = ebase + el;
    const float gate = 1.f / (1.f + __expf(-(g_s[w][el] + egb_s)));
    float dlt[4] = {b2s[j0], b2s[j0 + 1], b2s[j0 + 2], b2s[j0 + 3]};
    #pragma unroll
    for (int i2 = 0; i2 < 16; ++i2){
      const float gi = gelu_f(t_s[w][el][i2] + b1s[i2]);
      #pragma unroll
      for (int jj = 0; jj < 4; ++jj) dlt[jj] += gi * w2s[i2 * 16 + j0 + jj];
    }
    float rv[4]; float s1 = 0.f, s2 = 0.f;
    #pragma unroll
    for (int jj = 0; jj < 4; ++jj){
      rv[jj] = ldx(ea, (long long)eg2 * EDD + j0 + jj, fea) + 0.1f * gate * dlt[jj];
      s1 += rv[jj]; s2 += rv[jj] * rv[jj];
    }
    s1 += __shfl_xor(s1, 1, 64); s2 += __shfl_xor(s2, 1, 64);
    s1 += __shfl_xor(s1, 2, 64); s2 += __shfl_xor(s2, 2, 64);
    const float mu  = s1 * (1.f / 16.f);
    const float var = s2 * (1.f / 16.f) - mu * mu;
    const float inv = rsqrtf(var + 1e-5f);
    const long long ob = (long long)N_NODES * HD + (long long)eg2 * EDD + j0;
    #pragma unroll
    for (int jj = 0; jj < 4; ++jj)
      stx(dout, ob + jj, fo, (rv[jj] - mu) * inv * gns[j0 + jj] + bns[j0 + jj]);
  }
}

// ---------------- message GEMM over SORTED edges with segmented-reduce epilogue
// S[dst] += gelu([h[src]|e_new] @ msg_w1 + b1); grid (1250,4), 128x128, K=544.
// 2-phase double-buffered K-loop: prefetch kt+1 into regs before MFMA on kt,
// write to alternate LDS buffer after, ONE barrier per K-step.
__global__ __launch_bounds__(256, 4) void kmsg(
    const u16* __restrict__ hB, const void* __restrict__ dout,
    const u16* __restrict__ W1T, const void* __restrict__ msg_b1,
    const int* __restrict__ F,
    const int* __restrict__ sSrc, const int* __restrict__ sDst,
    const int* __restrict__ sIdx,
    float* __restrict__ agg)
{
  __shared__ __align__(16) float SMEM[8192];  // 32KB: dbuf As/Bs; Sf aliases
  u16*   bufU = (u16*)SMEM;    // buf b: A at b*8192, B at b*8192+4096 (u16 units)
  float* Sf   = SMEM;          // [128*34] f32, epilogue only
  __shared__ int src_s[128];
  __shared__ int dst_s[128];
  __shared__ int idx_s[128];
  const int tid = threadIdx.x;
  const int fw = F[2], fo = F[11];
  const void* e_base = fo ? (const void*)((const float*)dout + (size_t)N_NODES * HD)
                          : (const void*)((const u16*)dout + (size_t)N_NODES * HD);
  const int row0 = blockIdx.x * 128, n0 = blockIdx.y * 128;
  if (tid < 128){
    src_s[tid] = sSrc[row0 + tid];
    dst_s[tid] = sDst[row0 + tid];
    idx_s[tid] = sIdx[row0 + tid];
  }
  __syncthreads();
  f32x4 acc[4][4];
  f32x4 z4 = {0.f, 0.f, 0.f, 0.f};
  #pragma unroll
  for (int i = 0; i < 4; ++i)
    #pragma unroll
    for (int j = 0; j < 4; ++j) acc[i][j] = z4;
  const int w = tid >> 6, l = tid & 63;
  const int wr = w >> 1, wc = w & 1, lm = l & 15, lk = l >> 4;
  // hoisted per-thread staging addresses (loop-invariant gathers)
  const int mA = tid >> 2, kqA = tid & 3;
  const u16* a0 = hB + (size_t)src_s[mA] * HD + kqA * 8;
  const u16* a1 = hB + (size_t)src_s[mA + 64] * HD + kqA * 8;
  const u16* b0 = W1T + (size_t)(n0 + mA) * 544 + kqA * 8;
  const u16* b1 = W1T + (size_t)(n0 + mA + 64) * 544 + kqA * 8;
  const int wA0 = mA * 32 + swz8(mA, kqA);
  const int wA1 = (mA + 64) * 32 + swz8(mA + 64, kqA);
  const long long eidx0 = (long long)idx_s[mA] * EDD + kqA * 8;
  const long long eidx1 = (long long)idx_s[mA + 64] * EDD + kqA * 8;
  int roA[4], roB[4];
  #pragma unroll
  for (int i = 0; i < 4; ++i){ int R = wr * 64 + i * 16 + lm; roA[i] = R * 32 + swz8(R, lk); }
  #pragma unroll
  for (int j = 0; j < 4; ++j){ int R = wc * 64 + j * 16 + lm; roB[j] = R * 32 + swz8(R, lk) + 4096; }
  // prologue: stage kt=0 into buffer 0
  *(uint4*)(bufU + wA0)        = *(const uint4*)a0;
  *(uint4*)(bufU + wA1)        = *(const uint4*)a1;
  *(uint4*)(bufU + 4096 + wA0) = *(const uint4*)b0;
  *(uint4*)(bufU + 4096 + wA1) = *(const uint4*)b1;
  __syncthreads();
  for (int kt = 0; kt < 17; ++kt){
    const int cb = (kt & 1) << 13;   // current buffer base (u16 units)
    const int nb = 8192 - cb;        // next buffer base
    uint4 rA0, rA1, rB0, rB1;
    if (kt < 16){
      const int kk = (kt + 1) * 32;
      if (kt < 15){
        rA0 = *(const uint4*)(a0 + kk);
        rA1 = *(const uint4*)(a1 + kk);
      } else {
        // tail tile kt+1==16: e_new features (kq<2), zeros (kq>=2)
        if (kqA < 2){
          rA0 = __builtin_bit_cast(uint4, ld8(e_base, eidx0, fo));
          rA1 = __builtin_bit_cast(uint4, ld8(e_base, eidx1, fo));
        } else {
          uint4 z = {0,0,0,0}; rA0 = z; rA1 = z;
        }
      }
      rB0 = *(const uint4*)(b0 + kk);
      rB1 = *(const uint4*)(b1 + kk);
    }
    bf16x8 af[4], bfv[4];
    #pragma unroll
    for (int i = 0; i < 4; ++i) af[i]  = *(const bf16x8*)(bufU + cb + roA[i]);
    #pragma unroll
    for (int j = 0; j < 4; ++j) bfv[j] = *(const bf16x8*)(bufU + cb + roB[j]);
    #pragma unroll
    for (int i = 0; i < 4; ++i)
      #pragma unroll
      for (int j = 0; j < 4; ++j)
        acc[i][j] = mfma16(af[i], bfv[j], acc[i][j]);
    if (kt < 16){
      *(uint4*)(bufU + nb + wA0)        = rA0;
      *(uint4*)(bufU + nb + wA1)        = rA1;
      *(uint4*)(bufU + nb + 4096 + wA0) = rB0;
      *(uint4*)(bufU + nb + 4096 + wA1) = rB1;
    }
    __syncthreads();
  }
  // epilogue: per j, dump 128x32 tile to LDS, segment-reduce over sorted dst runs
  for (int j = 0; j < 4; ++j){
    const int col = n0 + wc * 64 + j * 16 + lm;
    const float bias = ldx(msg_b1, col, fw);
    #pragma unroll
    for (int i = 0; i < 4; ++i)
      #pragma unroll
      for (int r = 0; r < 4; ++r)
        Sf[(wr * 64 + i * 16 + lk * 4 + r) * 34 + wc * 16 + lm] =
            gelu_f(acc[i][j][r] + bias);
    __syncthreads();
    const int cj = tid & 31, chunk = tid >> 5;
    const int acol = n0 + (cj >> 4) * 64 + j * 16 + (cj & 15);
    const int rbase = chunk * 16;
    float run = Sf[rbase * 34 + cj];
    int cur = dst_s[rbase];
    #pragma unroll 4
    for (int rr = 1; rr < 16; ++rr){
      const int dn = dst_s[rbase + rr];
      const float v = Sf[(rbase + rr) * 34 + cj];
      if (dn == cur) run += v;
      else { atomicAdd(&agg[(size_t)cur * HD + acol], run); run = v; cur = dn; }
    }
    atomicAdd(&agg[(size_t)cur * HD + acol], run);
    __syncthreads();
  }
}

// ---------------- aggM = bf16(S @ msg_w2 + deg*b2)   grid (79,8), BM=128 BN=64
__global__ __launch_bounds__(256, 4) void kagg2(
    const float* __restrict__ S, const u16* __restrict__ W2T,
    const void* __restrict__ msg_b2, const int* __restrict__ F,
    const int* __restrict__ deg, u16* __restrict__ aggM)
{
  __shared__ u16 As[128 * 32];
  __shared__ u16 Bs[64 * 32];
  const int tid = threadIdx.x;
  const int fw = F[3];
  const int row0 = blockIdx.x * 128, n0 = blockIdx.y * 64;
  f32x4 acc[2][4];
  f32x4 z4 = {0.f, 0.f, 0.f, 0.f};
  #pragma unroll
  for (int i = 0; i < 2; ++i)
    #pragma unroll
    for (int j = 0; j < 4; ++j) acc[i][j] = z4;
  const int w = tid >> 6, l = tid & 63;
  const int lm = l & 15, lk = l >> 4;
  const int am = tid >> 1, ah = tid & 1;
  const int agr = row0 + am;
  const int nB = tid >> 2, kqB = tid & 3;
  for (int kt = 0; kt < 16; ++kt){
    const int kk = kt * 32;
    u16 tmp[16];
    if (agr < N_NODES){
      const float4* sp = (const float4*)(S + (size_t)agr * HD + kk + ah * 16);
      #pragma unroll
      for (int q = 0; q < 4; ++q){
        float4 v = sp[q];
        tmp[q*4+0] = f2bf(v.x); tmp[q*4+1] = f2bf(v.y);
        tmp[q*4+2] = f2bf(v.z); tmp[q*4+3] = f2bf(v.w);
      }
    } else {
      #pragma unroll
      for (int q = 0; q < 16; ++q) tmp[q] = 0;
    }
    *(uint4*)&As[am * 32 + swz8(am, ah * 2)]     = *(uint4*)&tmp[0];
    *(uint4*)&As[am * 32 + swz8(am, ah * 2 + 1)] = *(uint4*)&tmp[8];
    *(uint4*)&Bs[nB * 32 + swz8(nB, kqB)] =
        *(const uint4*)(W2T + (size_t)(n0 + nB) * 512 + kk + kqB * 8);
    __syncthreads();
    bf16x8 af[2], bfv[4];
    #pragma unroll
    for (int i = 0; i < 2; ++i){
      const int R = w * 32 + i * 16 + lm;
      af[i] = *(const bf16x8*)&As[R * 32 + swz8(R, lk)];
    }
    #pragma unroll
    for (int j = 0; j < 4; ++j){
      const int R = j * 16 + lm;
      bfv[j] = *(const bf16x8*)&Bs[R * 32 + swz8(R, lk)];
    }
    #pragma unroll
    for (int i = 0; i < 2; ++i)
      #pragma unroll
      for (int j = 0; j < 4; ++j)
        acc[i][j] = mfma16(af[i], bfv[j], acc[i][j]);
    __syncthreads();
  }
  #pragma unroll
  for (int j = 0; j < 4; ++j){
    const int col = n0 + j * 16 + lm;
    const float b2v = ldx(msg_b2, col, fw);
    #pragma unroll
    for (int i = 0; i < 2; ++i){
      const int rb = row0 + w * 32 + i * 16 + lk * 4;
      #pragma unroll
      for (int r = 0; r < 4; ++r){
        int gr = rb + r;
        if (gr < N_NODES)
          aggM[(size_t)gr * HD + col] = f2bf(acc[i][j][r] + (float)deg[gr] * b2v);
      }
    }
  }
}

// ---------------- U = bf16(gelu([h|aggM] @ upd_w1 + b1))  grid (79,8), K=1024
__global__ __launch_bounds__(256, 4) void kupd1(
    const u16* __restrict__ hB, const u16* __restrict__ aggM,
    const u16* __restrict__ WU1T, const void* __restrict__ upd_b1,
    const int* __restrict__ F, u16* __restrict__ U)
{
  __shared__ u16 As[128 * 32];
  __shared__ u16 Bs[64 * 32];
  const int tid = threadIdx.x;
  const int fw = F[4];
  const int row0 = blockIdx.x * 128, n0 = blockIdx.y * 64;
  f32x4 acc[2][4];
  f32x4 z4 = {0.f, 0.f, 0.f, 0.f};
  #pragma unroll
  for (int i = 0; i < 2; ++i)
    #pragma unroll
    for (int j = 0; j < 4; ++j) acc[i][j] = z4;
  const int w = tid >> 6, l = tid & 63;
  const int lm = l & 15, lk = l >> 4;
  const int nB = tid >> 2, kqB = tid & 3;
  for (int kt = 0; kt < 32; ++kt){
    const int kk = kt * 32;
    #pragma unroll
    for (int i = 0; i < 2; ++i){
      int t = tid + i * 256;
      int m = t >> 2, kq = t & 3, c = kk + kq * 8;
      int gr = row0 + m; if (gr > N_NODES - 1) gr = N_NODES - 1;
      if (kk < 512) *(uint4*)&As[m * 32 + swz8(m, kq)] = *(const uint4*)(hB + (size_t)gr * HD + c);
      else          *(uint4*)&As[m * 32 + swz8(m, kq)] = *(const uint4*)(aggM + (size_t)gr * HD + (c - 512));
    }
    *(uint4*)&Bs[nB * 32 + swz8(nB, kqB)] =
        *(const uint4*)(WU1T + (size_t)(n0 + nB) * 1024 + kk + kqB * 8);
    __syncthreads();
    bf16x8 af[2], bfv[4];
    #pragma unroll
    for (int i = 0; i < 2; ++i){
      const int R = w * 32 + i * 16 + lm;
      af[i] = *(const bf16x8*)&As[R * 32 + swz8(R, lk)];
    }
    #pragma unroll
    for (int j = 0; j < 4; ++j){
      const int R = j * 16 + lm;
      bfv[j] = *(const bf16x8*)&Bs[R * 32 + swz8(R, lk)];
    }
    #pragma unroll
    for (int i = 0; i < 2; ++i)
      #pragma unroll
      for (int j = 0; j < 4; ++j)
        acc[i][j] = mfma16(af[i], bfv[j], acc[i][j]);
    __syncthreads();
  }
  #pragma unroll
  for (int j = 0; j < 4; ++j){
    const int col = n0 + j * 16 + lm;
    const float bias = ldx(upd_b1, col, fw);
    #pragma unroll
    for (int i = 0; i < 2; ++i){
      const int rb = row0 + w * 32 + i * 16 + lk * 4;
      #pragma unroll
      for (int r = 0; r < 4; ++r){
        int gr = rb + r;
        if (gr < N_NODES)
          U[(size_t)gr * HD + col] = f2bf(gelu_f(acc[i][j][r] + bias));
      }
    }
  }
}

// ---------------- h2b = bf16(U @ upd_w2 + b2)   grid (79,8), K=512
__global__ __launch_bounds__(256, 4) void kupd2(
    const u16* __restrict__ U, const u16* __restrict__ WU2T,
    const void* __restrict__ upd_b2, const int* __restrict__ F,
    u16* __restrict__ h2b)
{
  __shared__ u16 As[128 * 32];
  __shared__ u16 Bs[64 * 32];
  const int tid = threadIdx.x;
  const int fw = F[5];
  const int row0 = blockIdx.x * 128, n0 = blockIdx.y * 64;
  f32x4 acc[2][4];
  f32x4 z4 = {0.f, 0.f, 0.f, 0.f};
  #pragma unroll
  for (int i = 0; i < 2; ++i)
    #pragma unroll
    for (int j = 0; j < 4; ++j) acc[i][j] = z4;
  const int w = tid >> 6, l = tid & 63;
  const int lm = l & 15, lk = l >> 4;
  const int nB = tid >> 2, kqB = tid & 3;
  for (int kt = 0; kt < 16; ++kt){
    const int kk = kt * 32;
    #pragma unroll
    for (int i = 0; i < 2; ++i){
      int t = tid + i * 256;
      int m = t >> 2, kq = t & 3;
      int gr = row0 + m; if (gr > N_NODES - 1) gr = N_NODES - 1;
      *(uint4*)&As[m * 32 + swz8(m, kq)] = *(const uint4*)(U + (size_t)gr * HD + kk + kq * 8);
    }
    *(uint4*)&Bs[nB * 32 + swz8(nB, kqB)] =
        *(const uint4*)(WU2T + (size_t)(n0 + nB) * 512 + kk + kqB * 8);
    __syncthreads();
    bf16x8 af[2], bfv[4];
    #pragma unroll
    for (int i = 0; i < 2; ++i){
      const int R = w * 32 + i * 16 + lm;
      af[i] = *(const bf16x8*)&As[R * 32 + swz8(R, lk)];
    }
    #pragma unroll
    for (int j = 0; j < 4; ++j){
      const int R = j * 16 + lm;
      bfv[j] = *(const bf16x8*)&Bs[R * 32 + swz8(R, lk)];
    }
    #pragma unroll
    for (int i = 0; i < 2; ++i)
      #pragma unroll
      for (int j = 0; j < 4; ++j)
        acc[i][j] = mfma16(af[i], bfv[j], acc[i][j]);
    __syncthreads();
  }
  #pragma unroll
  for (int j = 0; j < 4; ++j){
    const int col = n0 + j * 16 + lm;
    const float bias = ldx(upd_b2, col, fw);
    #pragma unroll
    for (int i = 0; i < 2; ++i){
      const int rb = row0 + w * 32 + i * 16 + lk * 4;
      #pragma unroll
      for (int r = 0; r < 4; ++r){
        int gr = rb + r;
        if (gr < N_NODES)
          h2b[(size_t)gr * HD + col] = f2bf(acc[i][j][r] + bias);
      }
    }
  }
}

// ---------------- h_out = LN(h + h2)   grid 2500, 4 rows/block
__global__ __launch_bounds__(256) void kln(
    const void* __restrict__ h, const u16* __restrict__ h2b,
    const void* __restrict__ gg, const void* __restrict__ bbv,
    const int* __restrict__ F, void* __restrict__ dout)
{
  const int fh = F[0], fng = F[9], fo = F[11];
  const int w = threadIdx.x >> 6, l = threadIdx.x & 63;
  const int row = blockIdx.x * 4 + w;
  float x[8];
  #pragma unroll
  for (int j = 0; j < 8; ++j){
    const long long idx = (long long)row * HD + l * 8 + j;
    x[j] = ldx(h, idx, fh) + bf2f(h2b[idx]);
  }
  float s1 = 0.f, s2 = 0.f;
  #pragma unroll
  for (int j = 0; j < 8; ++j){ s1 += x[j]; s2 += x[j] * x[j]; }
  #pragma unroll
  for (int m = 1; m < 64; m <<= 1){ s1 += __shfl_xor(s1, m, 64); s2 += __shfl_xor(s2, m, 64); }
  const float mu  = s1 * (1.f / 512.f);
  const float var = s2 * (1.f / 512.f) - mu * mu;
  const float inv = rsqrtf(var + 1e-5f);
  #pragma unroll
  for (int j = 0; j < 8; ++j){
    const float gf = ldx(gg,  l * 8 + j, fng);
    const float bf = ldx(bbv, l * 8 + j, fng);
    stx(dout, (long long)row * HD + l * 8 + j, fo, (x[j] - mu) * inv * gf + bf);
  }
}

// ---------------- workspace layout (bytes), total 35,448,064 (verified fits)
#define OFF_S     0u            // N*512 f32 (scatter accum; aliased as U bf16)
#define OFF_DEG   20480000u     // N ints
#define OFF_CUR   20520000u     // N ints (sort cursors)
#define OFF_F     20560000u     // 16 ints
#define OFF_START 20560064u     // N ints
#define OFF_AGGM  20600064u     // N*512 bf16 (aliased as h2b)
#define OFF_W1T   30840064u     // 512*544 bf16
#define OFF_W2T   31397120u     // 512*512 bf16
#define OFF_WU1T  31921408u     // 512*1024 bf16
#define OFF_WU2T  32969984u     // 512*512 bf16
#define OFF_WET   33494272u     // 16*1056 bf16
#define OFF_SSRC  33528064u     // E ints
#define OFF_SDST  34168064u     // E ints
#define OFF_SIDX  34808064u     // E ints
#define WS_NEEDED 35448064u

extern "C" void kernel_launch(void* const* d_in, const int* in_sizes, int n_in,
                              void* d_out, int out_size, void* d_ws, size_t ws_size,
                              hipStream_t stream)
{
  const void* h      = d_in[0];
  const void* ea     = d_in[1];
  const void* msg_w1 = d_in[2];
  const void* msg_b1 = d_in[3];
  const void* msg_w2 = d_in[4];
  const void* msg_b2 = d_in[5];
  const void* upd_w1 = d_in[6];
  const void* upd_b1 = d_in[7];
  const void* upd_w2 = d_in[8];
  const void* upd_b2 = d_in[9];
  const void* norm_g = d_in[10];
  const void* norm_b = d_in[11];
  const void* em_w1  = d_in[12];
  const void* em_b1  = d_in[13];
  const void* em_w2  = d_in[14];
  const void* em_b2  = d_in[15];
  const void* eg_w   = d_in[16];
  const void* eg_b   = d_in[17];
  const void* en_g   = d_in[18];
  const void* en_b   = d_in[19];
  const int* eidx    = (const int*)d_in[20];
  const int* srcI = eidx;
  const int* dstI = eidx + N_EDGES;

  float sent = 0.f;
  if (ws_size < (size_t)WS_NEEDED)            sent = 1000.f;
  else if (n_in != 21)                        sent = 2000.f;
  else if (in_sizes[0]  != N_NODES * HD)      sent = 3000.f;
  else if (in_sizes[20] != 2 * N_EDGES)       sent = 4000.f;
  else if (out_size != N_NODES*HD + N_EDGES*EDD) sent = 5000.f;
  if (sent != 0.f){
    kfill<<<(out_size + 255)/256, 256, 0, stream>>>((u16*)d_out, out_size, sent);
    return;
  }

  char* ws = (char*)d_ws;
  float* S     = (float*)(ws + OFF_S);
  u16*   U     = (u16*)(ws + OFF_S);      // alias: after kagg2 consumed S
  int*   deg   = (int*)(ws + OFF_DEG);
  int*   cur   = (int*)(ws + OFF_CUR);
  int*   F     = (int*)(ws + OFF_F);
  int*   start = (int*)(ws + OFF_START);
  u16*   aggM  = (u16*)(ws + OFF_AGGM);
  u16*   h2b   = (u16*)(ws + OFF_AGGM);   // alias: after kupd1 consumed aggM
  u16*   W1T   = (u16*)(ws + OFF_W1T);
  u16*   W2T   = (u16*)(ws + OFF_W2T);
  u16*   WU1T  = (u16*)(ws + OFF_WU1T);
  u16*   WU2T  = (u16*)(ws + OFF_WU2T);
  u16*   WET   = (u16*)(ws + OFF_WET);
  int*   sSrc  = (int*)(ws + OFF_SSRC);
  int*   sDst  = (int*)(ws + OFF_SDST);
  int*   sIdx  = (int*)(ws + OFF_SIDX);

  // hB (bf16 h) lives in d_out's h_out region (dead until kln rewrites it).
  u16* hB = (u16*)d_out;

  // zero S + deg + cursors in one memset (contiguous)
  hipMemsetAsync(S, 0, (size_t)OFF_F, stream);

  kprobe<<<1, 64, 0, stream>>>(h, ea, msg_w1, msg_w2, upd_w1, upd_w2,
                               em_w1, em_w2, eg_w, norm_g, en_g, F);

  kcvt<<<2500, 256, 0, stream>>>(h, hB, F);

  ktranspose<<<(512*544  + 255)/256, 256, 0, stream>>>(msg_w1, W1T, 528, 512, 544, 512, F, 2);
  ktranspose<<<(512*512  + 255)/256, 256, 0, stream>>>(msg_w2, W2T, 512, 512, 512, 512, F, 3);
  ktranspose<<<(512*1024 + 255)/256, 256, 0, stream>>>(upd_w1, WU1T, 1024, 512, 1024, 512, F, 4);
  ktranspose<<<(512*512  + 255)/256, 256, 0, stream>>>(upd_w2, WU2T, 512, 512, 512, 512, F, 5);
  ktranspose<<<(16*1056  + 255)/256, 256, 0, stream>>>(em_w1, WET, 1040, 16, 1056, 16, F, 6);

  kdeg<<<(N_EDGES + 255)/256, 256, 0, stream>>>(dstI, deg);
  kscan<<<1, 256, 0, stream>>>(deg, start);
  kscatter<<<(N_EDGES + 255)/256, 256, 0, stream>>>(srcI, dstI, start, cur,
                                                    sSrc, sDst, sIdx);

  kedge<<<625, 256, 0, stream>>>(hB, ea, WET, eg_w, em_b1, em_w2, em_b2, eg_b,
                                 en_g, en_b, F, srcI, dstI, d_out);
  kmsg<<<dim3(1250, 4), 256, 0, stream>>>(hB, d_out, W1T, msg_b1, F,
                                          sSrc, sDst, sIdx, S);
  kagg2<<<dim3(79, 8), 256, 0, stream>>>(S, W2T, msg_b2, F, deg, aggM);
  kupd1<<<dim3(79, 8), 256, 0, stream>>>(hB, aggM, WU1T, upd_b1, F, U);
  kupd2<<<dim3(79, 8), 256, 0, stream>>>(U, WU2T, upd_b2, F, h2b);
  kln<<<2500, 256, 0, stream>>>(h, h2b, norm_g, norm_b, F, d_out);
}